// Round 1
// baseline (2146.717 us; speedup 1.0000x reference)
//
#include <hip/hip_runtime.h>
#include <cstdint>
#include <cstddef>

// RWKV_Tmix_headmixer — correctness-first f32 baseline.
// B=1, T=2048, C=1024, H=16, K=64.
//
// Decomposition:
//  1. prep:    dxprev = shift(x) - x ; z = x + dxprev*maa_x
//  2. lora1:   xxx = tanh(z @ w1[1024,96]) ; ha = tanh(x @ hw1[1024,128])
//  3. mix:     xq/xk/xv = x + dxprev*(maa_{r,k,v} + xxx_n @ w2_n)
//  4. hm:      hm[n,t,h] = (ha[t,n,:] @ hw2[n]) / 16   (pre_q,pre_k,post_q,post_k)
//  5. gemm+LN: q = LN(xq@w_r) f32 ; k,v = LN(..) stored bf16 (attention staging)
//  6. attn A:  exact softmax stats m,l per (h,t).  Head-coupled pre-mix folded
//              into additive e_pre(t,s) = a*(1+Σ_h pre_k[s]) + Σ_h y0*pre_k[s].
//  7. attn B:  recompute scores, p = exp(y3-m)/l, p2 = p + e_post(t,s),
//              out += p2 * V  (exact, no online rescale needed).
//  8. LN + gemm with w_o -> d_out.

#define C_DIM 1024
#define TT 4          // t-rows per attention block
#define SS 8          // s-cols per attention tile
#define KS_STR 68     // padded per-head stride in LDS (64 + 4 -> conflict-free)
#define KS_ROW (16*KS_STR)
#define KS_ELEMS (SS*KS_ROW)   // 8704 floats = 34 KB

typedef unsigned short ushort_t;

__device__ __forceinline__ unsigned int f2bf_u(float f) {
  unsigned int u = __float_as_uint(f);
  return (u + 0x7fffu + ((u >> 16) & 1u)) >> 16;   // RNE
}

// ---------------- 1. prep ----------------
__global__ __launch_bounds__(256) void prep_kernel(
    const float* __restrict__ x, const float* __restrict__ shift,
    const float* __restrict__ maa_x,
    float* __restrict__ dxprev, float* __restrict__ z)
{
  const int t = blockIdx.x;
  const int c = threadIdx.x * 4;
  const size_t base = (size_t)t * C_DIM + c;
  const float4 xc = *(const float4*)&x[base];
  const float4 xp = (t == 0) ? *(const float4*)&shift[c]
                             : *(const float4*)&x[base - C_DIM];
  const float4 mx = *(const float4*)&maa_x[c];
  float4 d, zz;
  d.x = xp.x - xc.x; d.y = xp.y - xc.y; d.z = xp.z - xc.z; d.w = xp.w - xc.w;
  zz.x = xc.x + d.x*mx.x; zz.y = xc.y + d.y*mx.y;
  zz.z = xc.z + d.z*mx.z; zz.w = xc.w + d.w*mx.w;
  *(float4*)&dxprev[base] = d;
  *(float4*)&z[base] = zz;
}

// ---------------- 2. lora1: xxx & ha ----------------
__global__ __launch_bounds__(256) void lora1_kernel(
    const float* __restrict__ z, const float* __restrict__ x,
    const float* __restrict__ w1, const float* __restrict__ hw1,
    float* __restrict__ xxx, float* __restrict__ ha)
{
  __shared__ float zr[4][C_DIM];
  __shared__ float xr[4][C_DIM];
  const int t0 = blockIdx.x * 4;
  const int tid = threadIdx.x;
  #pragma unroll
  for (int i = 0; i < 4; i++) {
    const int u = tid + i*256;
    const int r = u >> 8;
    const int cc = (u & 255) * 4;
    *(float4*)&zr[r][cc] = *(const float4*)&z[(size_t)(t0+r)*C_DIM + cc];
    *(float4*)&xr[r][cc] = *(const float4*)&x[(size_t)(t0+r)*C_DIM + cc];
  }
  __syncthreads();
  float a0=0.f, a1=0.f, a2=0.f, a3=0.f;
  if (tid < 96) {
    #pragma unroll 4
    for (int cc = 0; cc < C_DIM; cc++) {
      const float w = w1[(size_t)cc*96 + tid];
      a0 += zr[0][cc]*w; a1 += zr[1][cc]*w; a2 += zr[2][cc]*w; a3 += zr[3][cc]*w;
    }
    xxx[(size_t)(t0+0)*96 + tid] = tanhf(a0);
    xxx[(size_t)(t0+1)*96 + tid] = tanhf(a1);
    xxx[(size_t)(t0+2)*96 + tid] = tanhf(a2);
    xxx[(size_t)(t0+3)*96 + tid] = tanhf(a3);
  } else if (tid < 224) {
    const int j = tid - 96;
    #pragma unroll 4
    for (int cc = 0; cc < C_DIM; cc++) {
      const float w = hw1[(size_t)cc*128 + j];
      a0 += xr[0][cc]*w; a1 += xr[1][cc]*w; a2 += xr[2][cc]*w; a3 += xr[3][cc]*w;
    }
    ha[(size_t)(t0+0)*128 + j] = tanhf(a0);
    ha[(size_t)(t0+1)*128 + j] = tanhf(a1);
    ha[(size_t)(t0+2)*128 + j] = tanhf(a2);
    ha[(size_t)(t0+3)*128 + j] = tanhf(a3);
  }
}

// ---------------- 3. mix: xq/xk/xv ----------------
__global__ __launch_bounds__(256) void mix_kernel(
    const float* __restrict__ x, const float* __restrict__ dxp,
    const float* __restrict__ xxx,
    const float* __restrict__ maa_r, const float* __restrict__ maa_k,
    const float* __restrict__ maa_v, const float* __restrict__ w2,
    float* __restrict__ xq, float* __restrict__ xk, float* __restrict__ xv)
{
  __shared__ float xs[96];
  const int t = blockIdx.x;
  const int tid = threadIdx.x;
  if (tid < 96) xs[tid] = xxx[(size_t)t*96 + tid];
  __syncthreads();
  const int c = tid * 4;
  const size_t base = (size_t)t*C_DIM + c;
  const float4 xc = *(const float4*)&x[base];
  const float4 dx = *(const float4*)&dxp[base];
  const float* maas[3] = {maa_r, maa_k, maa_v};
  float* outs[3] = {xq, xk, xv};
  #pragma unroll
  for (int n = 0; n < 3; n++) {
    const float4 mv = *(const float4*)&maas[n][c];
    float m0 = mv.x, m1 = mv.y, m2 = mv.z, m3 = mv.w;
    #pragma unroll 8
    for (int d = 0; d < 32; d++) {
      const float xval = xs[n*32 + d];
      const float4 w = *(const float4*)&w2[((size_t)n*32 + d)*C_DIM + c];
      m0 += xval*w.x; m1 += xval*w.y; m2 += xval*w.z; m3 += xval*w.w;
    }
    *(float4*)&outs[n][base] = make_float4(xc.x + dx.x*m0, xc.y + dx.y*m1,
                                           xc.z + dx.z*m2, xc.w + dx.w*m3);
  }
}

// ---------------- 4. hm: per-head mixing coeffs ----------------
__global__ __launch_bounds__(256) void hm_kernel(
    const float* __restrict__ ha, const float* __restrict__ hw2,
    float* __restrict__ hm, int T)
{
  const int t = blockIdx.x*4 + (threadIdx.x >> 6);
  const int u = threadIdx.x & 63;
  const int n = u >> 4, h = u & 15;
  float s = 0.f;
  #pragma unroll 8
  for (int d = 0; d < 32; d++)
    s += ha[(size_t)t*128 + n*32 + d] * hw2[(size_t)(n*32 + d)*16 + h];
  hm[((size_t)n*T + t)*16 + h] = s * (1.f/16.f);
}

// ---------------- 5a. f32 tiled GEMM: C = A @ B ----------------
// A [M,K] row-major, B [K,N] row-major. 128x64 tile, BK=16, 8x4 per thread.
__global__ __launch_bounds__(256) void gemm_f32(
    const float* __restrict__ A, const float* __restrict__ B,
    float* __restrict__ Cm, int M, int N, int K)
{
  __shared__ float As[16][128];
  __shared__ float Bs[16][64];
  const int bm = blockIdx.y * 128;
  const int bn = blockIdx.x * 64;
  const int tid = threadIdx.x;
  const int tx = tid & 15;
  const int ty = tid >> 4;
  float acc[8][4];
  #pragma unroll
  for (int i = 0; i < 8; i++)
    #pragma unroll
    for (int j = 0; j < 4; j++) acc[i][j] = 0.f;
  const int ar = tid >> 2;
  const int ac = (tid & 3) << 2;
  const int br = tid >> 4;
  const int bc = (tid & 15) << 2;
  for (int k0 = 0; k0 < K; k0 += 16) {
    #pragma unroll
    for (int rr = 0; rr < 2; rr++) {
      const int row = ar + rr*64;
      const float4 a4 = *(const float4*)&A[(size_t)(bm+row)*K + k0 + ac];
      As[ac+0][row] = a4.x; As[ac+1][row] = a4.y;
      As[ac+2][row] = a4.z; As[ac+3][row] = a4.w;
    }
    const float4 b4 = *(const float4*)&B[(size_t)(k0+br)*N + bn + bc];
    *(float4*)&Bs[br][bc] = b4;
    __syncthreads();
    #pragma unroll
    for (int kk = 0; kk < 16; kk++) {
      const float4 a0 = *(const float4*)&As[kk][ty*8];
      const float4 a1 = *(const float4*)&As[kk][ty*8+4];
      const float4 b0 = *(const float4*)&Bs[kk][tx*4];
      const float am[8] = {a0.x,a0.y,a0.z,a0.w,a1.x,a1.y,a1.z,a1.w};
      const float bn4[4] = {b0.x,b0.y,b0.z,b0.w};
      #pragma unroll
      for (int i = 0; i < 8; i++)
        #pragma unroll
        for (int j = 0; j < 4; j++) acc[i][j] += am[i]*bn4[j];
    }
    __syncthreads();
  }
  #pragma unroll
  for (int i = 0; i < 8; i++)
    *(float4*)&Cm[(size_t)(bm+ty*8+i)*N + bn + tx*4] =
        make_float4(acc[i][0], acc[i][1], acc[i][2], acc[i][3]);
}

// ---------------- 5b. row LayerNorm ----------------
template<int OUT_BF16>
__global__ __launch_bounds__(256) void ln_rows(
    const float* __restrict__ in, void* __restrict__ outp,
    const float* __restrict__ g, const float* __restrict__ b)
{
  __shared__ float red[4];
  const int t = blockIdx.x;
  const int tid = threadIdx.x;
  const int c = tid*4;
  const float4 v = *(const float4*)&in[(size_t)t*C_DIM + c];
  float s = v.x+v.y+v.z+v.w;
  #pragma unroll
  for (int off = 32; off > 0; off >>= 1) s += __shfl_down(s, off, 64);
  if ((tid & 63) == 0) red[tid >> 6] = s;
  __syncthreads();
  const float mean = (red[0]+red[1]+red[2]+red[3]) * (1.0f/C_DIM);
  __syncthreads();
  const float d0 = v.x-mean, d1 = v.y-mean, d2 = v.z-mean, d3 = v.w-mean;
  float q = d0*d0 + d1*d1 + d2*d2 + d3*d3;
  #pragma unroll
  for (int off = 32; off > 0; off >>= 1) q += __shfl_down(q, off, 64);
  if ((tid & 63) == 0) red[tid >> 6] = q;
  __syncthreads();
  const float var = (red[0]+red[1]+red[2]+red[3]) * (1.0f/C_DIM);
  const float rstd = rsqrtf(var + 1e-5f);
  const float4 gv = *(const float4*)&g[c];
  const float4 bv = *(const float4*)&b[c];
  const float o0 = d0*rstd*gv.x + bv.x;
  const float o1 = d1*rstd*gv.y + bv.y;
  const float o2 = d2*rstd*gv.z + bv.z;
  const float o3 = d3*rstd*gv.w + bv.w;
  if (OUT_BF16) {
    uint2 packed;
    packed.x = f2bf_u(o0) | (f2bf_u(o1) << 16);
    packed.y = f2bf_u(o2) | (f2bf_u(o3) << 16);
    *(uint2*)((ushort_t*)outp + (size_t)t*C_DIM + c) = packed;
  } else {
    *(float4*)((float*)outp + (size_t)t*C_DIM + c) = make_float4(o0,o1,o2,o3);
  }
}

// ---------------- attention helpers ----------------
// Stage an SS x 1024 bf16 tile into padded f32 LDS: ks[ss][head][64(+4 pad)].
__device__ __forceinline__ void load_tile_bf16(
    const ushort_t* __restrict__ src, float* __restrict__ dstbuf, int tid)
{
  #pragma unroll
  for (int i = 0; i < 4; i++) {
    const int u = tid + i*256;
    const int ss = u >> 7;
    const int c0 = (u & 127) << 3;
    const uint4 raw = *(const uint4*)(src + (size_t)ss*C_DIM + c0);
    float* dst = &dstbuf[ss*KS_ROW + (c0 >> 6)*KS_STR + (c0 & 63)];
    dst[0] = __uint_as_float(raw.x << 16);
    dst[1] = __uint_as_float(raw.x & 0xffff0000u);
    dst[2] = __uint_as_float(raw.y << 16);
    dst[3] = __uint_as_float(raw.y & 0xffff0000u);
    dst[4] = __uint_as_float(raw.z << 16);
    dst[5] = __uint_as_float(raw.z & 0xffff0000u);
    dst[6] = __uint_as_float(raw.w << 16);
    dst[7] = __uint_as_float(raw.w & 0xffff0000u);
  }
}

// ---------------- 6. attention phase A: softmax stats ----------------
// block: 256 threads = 16 h x 4 tt x 4 ssq.  Each thread owns one (h,t) q-row
// in registers and 2 of the 8 s-columns per tile.
__global__ __launch_bounds__(256) void attn_stats(
    const float* __restrict__ qf, const ushort_t* __restrict__ kbf,
    const float* __restrict__ hm, float* __restrict__ m_g,
    float* __restrict__ l_g, int T)
{
  __shared__ float ks[KS_ELEMS];
  __shared__ float y0s[SS][65];
  __shared__ float epre_s[TT][SS];
  __shared__ float mred[3][64];
  __shared__ float lred[3][64];

  const int tile = (int)gridDim.x - 1 - (int)blockIdx.x;  // longest-first
  const int t0 = tile * TT;
  const int tid = threadIdx.x;
  const int rid = tid & 63;
  const int ssq = tid >> 6;
  const int h = rid >> 2;
  const int tt = rid & 3;
  const int t = t0 + tt;

  float qreg[64];
  {
    const float* qp = qf + (size_t)t*C_DIM + h*64;
    #pragma unroll
    for (int k = 0; k < 64; k += 4) {
      const float4 v = *(const float4*)(qp + k);
      qreg[k]   = v.x * 0.125f;  // fold scale = K^-0.5
      qreg[k+1] = v.y * 0.125f;
      qreg[k+2] = v.z * 0.125f;
      qreg[k+3] = v.w * 0.125f;
    }
  }
  const float slope = exp2f(-0.5f * (float)(h + 1));
  float m_run = -INFINITY, l_run = 0.f;
  const int nS = t0 + TT;  // causal: s <= t < t0+TT

  for (int st = 0; st < nS; st += SS) {
    load_tile_bf16(kbf + (size_t)st*C_DIM, ks, tid);
    __syncthreads();
    #pragma unroll
    for (int j = 0; j < 2; j++) {
      const int ss = ssq*2 + j;
      const float* kp = &ks[ss*KS_ROW + h*KS_STR];
      float acc = 0.f;
      #pragma unroll
      for (int k = 0; k < 64; k += 4) {
        const float4 kv = *(const float4*)(kp + k);
        acc += qreg[k]*kv.x + qreg[k+1]*kv.y + qreg[k+2]*kv.z + qreg[k+3]*kv.w;
      }
      y0s[ss][rid] = acc;
    }
    __syncthreads();
    if (tid < 32) {  // cross-head pre-mix  e_pre(t,s)
      const int tt2 = tid >> 3, ss2 = tid & 7;
      const int s = st + ss2, tr = t0 + tt2;
      float a = 0.f, b0 = 0.f, spk = 0.f;
      #pragma unroll
      for (int h2 = 0; h2 < 16; h2++) {
        const float yv = y0s[ss2][h2*4 + tt2];
        a  += yv * hm[(size_t)tr*16 + h2];                 // pre_q (n=0)
        const float pk = hm[((size_t)T + s)*16 + h2];      // pre_k (n=1)
        b0 += yv * pk;
        spk += pk;
      }
      epre_s[tt2][ss2] = a*(1.f + spk) + b0;
    }
    __syncthreads();
    #pragma unroll
    for (int j = 0; j < 2; j++) {
      const int ss = ssq*2 + j;
      const int s = st + ss;
      if (s <= t) {
        const float y3 = y0s[ss][rid] + epre_s[tt][ss] - slope*(float)(t - s);
        if (y3 > m_run) {
          l_run = l_run * __expf(m_run - y3) + 1.f;
          m_run = y3;
        } else {
          l_run += __expf(y3 - m_run);
        }
      }
    }
    __syncthreads();
  }
  if (ssq > 0) { mred[ssq-1][rid] = m_run; lred[ssq-1][rid] = l_run; }
  __syncthreads();
  if (ssq == 0) {  // ssq0 always has s=0 valid -> m_run finite, no NaN path
    float M = m_run, L = l_run;
    #pragma unroll
    for (int q2 = 0; q2 < 3; q2++) {
      const float m2 = mred[q2][rid];
      const float l2 = lred[q2][rid];
      const float newM = fmaxf(M, m2);
      L = L * __expf(M - newM) + l2 * __expf(m2 - newM);
      M = newM;
    }
    m_g[(size_t)h*T + t] = M;
    l_g[(size_t)h*T + t] = L;
  }
}

// ---------------- 7. attention phase B: apply ----------------
__global__ __launch_bounds__(256) void attn_apply(
    const float* __restrict__ qf, const ushort_t* __restrict__ kbf,
    const ushort_t* __restrict__ vbf, const float* __restrict__ hm,
    const float* __restrict__ m_g, const float* __restrict__ l_g,
    float* __restrict__ out, int T)
{
  __shared__ float ks[KS_ELEMS];   // K tile, then V tile, then reduce scratch
  __shared__ float y0s[SS][65];    // y0, then p
  __shared__ float epre_s[TT][SS];
  __shared__ float epost_s[TT][SS];

  const int tile = (int)gridDim.x - 1 - (int)blockIdx.x;
  const int t0 = tile * TT;
  const int tid = threadIdx.x;
  const int rid = tid & 63;
  const int ssq = tid >> 6;
  const int h = rid >> 2;
  const int tt = rid & 3;
  const int t = t0 + tt;

  float qreg[64];
  {
    const float* qp = qf + (size_t)t*C_DIM + h*64;
    #pragma unroll
    for (int k = 0; k < 64; k += 4) {
      const float4 v = *(const float4*)(qp + k);
      qreg[k]   = v.x * 0.125f;
      qreg[k+1] = v.y * 0.125f;
      qreg[k+2] = v.z * 0.125f;
      qreg[k+3] = v.w * 0.125f;
    }
  }
  const float slope = exp2f(-0.5f * (float)(h + 1));
  const float m_fin = m_g[(size_t)h*T + t];
  const float inv_l = 1.f / l_g[(size_t)h*T + t];
  float acc[64];
  #pragma unroll
  for (int k = 0; k < 64; k++) acc[k] = 0.f;
  const int nS = t0 + TT;

  for (int st = 0; st < nS; st += SS) {
    load_tile_bf16(kbf + (size_t)st*C_DIM, ks, tid);
    __syncthreads();
    #pragma unroll
    for (int j = 0; j < 2; j++) {
      const int ss = ssq*2 + j;
      const float* kp = &ks[ss*KS_ROW + h*KS_STR];
      float a = 0.f;
      #pragma unroll
      for (int k = 0; k < 64; k += 4) {
        const float4 kv = *(const float4*)(kp + k);
        a += qreg[k]*kv.x + qreg[k+1]*kv.y + qreg[k+2]*kv.z + qreg[k+3]*kv.w;
      }
      y0s[ss][rid] = a;
    }
    __syncthreads();
    if (tid < 32) {
      const int tt2 = tid >> 3, ss2 = tid & 7;
      const int s = st + ss2, tr = t0 + tt2;
      float a = 0.f, b0 = 0.f, spk = 0.f;
      #pragma unroll
      for (int h2 = 0; h2 < 16; h2++) {
        const float yv = y0s[ss2][h2*4 + tt2];
        a  += yv * hm[(size_t)tr*16 + h2];
        const float pk = hm[((size_t)T + s)*16 + h2];
        b0 += yv * pk;
        spk += pk;
      }
      epre_s[tt2][ss2] = a*(1.f + spk) + b0;
    }
    __syncthreads();
    // p = exp(y3 - m)/l   (exact; 0 for masked)
    #pragma unroll
    for (int j = 0; j < 2; j++) {
      const int ss = ssq*2 + j;
      const int s = st + ss;
      float p = 0.f;
      if (s <= t) {
        const float y3 = y0s[ss][rid] + epre_s[tt][ss] - slope*(float)(t - s);
        p = __expf(y3 - m_fin) * inv_l;
      }
      y0s[ss][rid] = p;  // own slot only
    }
    __syncthreads();
    // V tile overwrites K tile (dead since the y0 barrier); post-mix in parallel
    load_tile_bf16(vbf + (size_t)st*C_DIM, ks, tid);
    if (tid < 32) {
      const int tt2 = tid >> 3, ss2 = tid & 7;
      const int s = st + ss2, tr = t0 + tt2;
      float cmix = 0.f, d0 = 0.f, spok = 0.f;
      #pragma unroll
      for (int h2 = 0; h2 < 16; h2++) {
        const float pv = y0s[ss2][h2*4 + tt2];
        cmix += pv * hm[((size_t)2*T + tr)*16 + h2];   // post_q (n=2)
        const float pk = hm[((size_t)3*T + s)*16 + h2]; // post_k (n=3)
        d0 += pv * pk;
        spok += pk;
      }
      epost_s[tt2][ss2] = cmix*(1.f + spok) + d0;
    }
    __syncthreads();
    // PV accumulate with p2 = p + e_post
    #pragma unroll
    for (int j = 0; j < 2; j++) {
      const int ss = ssq*2 + j;
      const int s = st + ss;
      if (s > t) continue;
      const float p2 = y0s[ss][rid] + epost_s[tt][ss];
      const float* vp = &ks[ss*KS_ROW + h*KS_STR];
      #pragma unroll
      for (int k = 0; k < 64; k += 4) {
        const float4 vv = *(const float4*)(vp + k);
        acc[k]   += p2*vv.x;
        acc[k+1] += p2*vv.y;
        acc[k+2] += p2*vv.z;
        acc[k+3] += p2*vv.w;
      }
    }
    __syncthreads();
  }
  // reduce partial sums across the 4 ssq groups (ks reused as scratch)
  if (ssq >= 2) {
    float* dst = &ks[(ssq-2)*4352 + rid*KS_STR];
    #pragma unroll
    for (int k = 0; k < 64; k += 4)
      *(float4*)(dst + k) = make_float4(acc[k], acc[k+1], acc[k+2], acc[k+3]);
  }
  __syncthreads();
  if (ssq < 2) {
    const float* src = &ks[ssq*4352 + rid*KS_STR];
    #pragma unroll
    for (int k = 0; k < 64; k++) acc[k] += src[k];
  }
  __syncthreads();
  if (ssq == 1) {
    float* dst = &ks[rid*KS_STR];
    #pragma unroll
    for (int k = 0; k < 64; k += 4)
      *(float4*)(dst + k) = make_float4(acc[k], acc[k+1], acc[k+2], acc[k+3]);
  }
  __syncthreads();
  if (ssq == 0) {
    const float* src = &ks[rid*KS_STR];
    float* op = out + (size_t)t*C_DIM + h*64;
    #pragma unroll
    for (int k = 0; k < 64; k += 4)
      *(float4*)(op + k) = make_float4(acc[k] + src[k], acc[k+1] + src[k+1],
                                       acc[k+2] + src[k+2], acc[k+3] + src[k+3]);
  }
}

// ---------------- launcher ----------------
extern "C" void kernel_launch(void* const* d_in, const int* in_sizes, int n_in,
                              void* d_out, int out_size, void* d_ws, size_t ws_size,
                              hipStream_t stream)
{
  const float* x      = (const float*)d_in[0];
  const float* shift  = (const float*)d_in[1];
  const float* maa_x  = (const float*)d_in[2];
  const float* maa_r  = (const float*)d_in[3];
  const float* maa_k  = (const float*)d_in[4];
  const float* maa_v  = (const float*)d_in[5];
  const float* w1     = (const float*)d_in[6];
  const float* w2     = (const float*)d_in[7];
  const float* hw1    = (const float*)d_in[8];
  const float* hw2    = (const float*)d_in[9];
  const float* w_r    = (const float*)d_in[10];
  const float* w_k    = (const float*)d_in[11];
  const float* w_v    = (const float*)d_in[12];
  const float* w_o    = (const float*)d_in[13];
  const float* ln_r_g = (const float*)d_in[14];
  const float* ln_r_b = (const float*)d_in[15];
  const float* ln_k_g = (const float*)d_in[16];
  const float* ln_k_b = (const float*)d_in[17];
  const float* ln_v_g = (const float*)d_in[18];
  const float* ln_v_b = (const float*)d_in[19];
  const float* ln_x_g = (const float*)d_in[20];
  const float* ln_x_b = (const float*)d_in[21];

  const int T = in_sizes[0] / C_DIM;      // 2048
  const size_t MM = (size_t)T * C_DIM;

  // workspace layout (floats), ~45 MB total with aliasing:
  float* ws     = (float*)d_ws;
  float* dxprev = ws;              // later: attn_out
  float* zbuf   = ws + MM;         // z -> GEMM tmp -> final LN out
  float* xq     = ws + 2*MM;       // later: q (f32)
  float* xk     = ws + 3*MM;       // later: k (bf16)
  float* xv     = ws + 4*MM;       // later: v (bf16)
  float* xxx    = ws + 5*MM;               // T*96
  float* ha     = xxx + (size_t)T*96;      // T*128
  float* hmb    = ha  + (size_t)T*128;     // 4*T*16
  float* m_g    = hmb + (size_t)T*64;      // 16*T
  float* l_g    = m_g + (size_t)T*16;      // 16*T

  float* qf = xq;
  ushort_t* kbf = (ushort_t*)xk;
  ushort_t* vbf = (ushort_t*)xv;
  float* attn_out = dxprev;

  prep_kernel<<<T, 256, 0, stream>>>(x, shift, maa_x, dxprev, zbuf);
  lora1_kernel<<<T/4, 256, 0, stream>>>(zbuf, x, w1, hw1, xxx, ha);
  mix_kernel<<<T, 256, 0, stream>>>(x, dxprev, xxx, maa_r, maa_k, maa_v, w2,
                                    xq, xk, xv);
  hm_kernel<<<T/4, 256, 0, stream>>>(ha, hw2, hmb, T);

  dim3 gg(C_DIM/64, T/128);
  gemm_f32<<<gg, 256, 0, stream>>>(xq, w_r, zbuf, T, C_DIM, C_DIM);
  ln_rows<0><<<T, 256, 0, stream>>>(zbuf, qf, ln_r_g, ln_r_b);
  gemm_f32<<<gg, 256, 0, stream>>>(xk, w_k, zbuf, T, C_DIM, C_DIM);
  ln_rows<1><<<T, 256, 0, stream>>>(zbuf, kbf, ln_k_g, ln_k_b);
  gemm_f32<<<gg, 256, 0, stream>>>(xv, w_v, zbuf, T, C_DIM, C_DIM);
  ln_rows<1><<<T, 256, 0, stream>>>(zbuf, vbf, ln_v_g, ln_v_b);

  attn_stats<<<T/TT, 256, 0, stream>>>(qf, kbf, hmb, m_g, l_g, T);
  attn_apply<<<T/TT, 256, 0, stream>>>(qf, kbf, vbf, hmb, m_g, l_g, attn_out, T);

  ln_rows<0><<<T, 256, 0, stream>>>(attn_out, zbuf, ln_x_g, ln_x_b);
  gemm_f32<<<gg, 256, 0, stream>>>(zbuf, w_o, (float*)d_out, T, C_DIM, C_DIM);
}

// Round 2
// 684.150 us; speedup vs baseline: 3.1378x; 3.1378x over previous
//
#include <hip/hip_runtime.h>
#include <cstdint>
#include <cstddef>

// RWKV_Tmix_headmixer — round 2: MFMA everywhere.
// B=1, T=2048, C=1024, H=16, K=64.
//
// mfma_f32_16x16x32_bf16 layout (per guide, HW-verified):
//   A-frag: lane reads A[row = l&15][k = (l>>4)*8 + j], j=0..7 (16B contig)
//   B-frag: lane reads B^T-ish: elems (k=(l>>4)*8+j, col=l&15) i.e. rows of a
//           [col][k]-major buffer (16B contig)
//   D: col = lane&15, row = (lane>>4)*4 + reg
//
// Attention: two-phase, S^T = mfma(K,Q) so lane holds 4 consecutive s per t.
// Head-coupling folded additively:
//   e_pre  = a(1+spk) + b0,  a = sum_h y0*pre_q[t,h], b0 = sum_h y0*pre_k[s,h]
//   e_post = c(1+spok) + d0, from normalized p (masked p = 0 -> e_post = 0)

#define C_DIM 1024
#define HEADS 16
#define TTL 32
#define STL 32
#define SCHUNK 256
#define PADS 40          // ybuf inner stride (bf16) -> conflict-free b128 reads
#define EPS_STR 36       // e_pre/e_post f32 stride

typedef unsigned short ushort_t;
typedef __attribute__((ext_vector_type(8))) short bf16x8;
typedef __attribute__((ext_vector_type(4))) float f32x4;

#define MFMA16(a, b, c) __builtin_amdgcn_mfma_f32_16x16x32_bf16(a, b, c, 0, 0, 0)

__device__ __forceinline__ unsigned int f2bf_u(float f) {
  unsigned int u = __float_as_uint(f);
  return (u + 0x7fffu + ((u >> 16) & 1u)) >> 16;   // RNE
}
__device__ __forceinline__ float bf2f(ushort_t u) {
  return __uint_as_float(((unsigned int)u) << 16);
}
__device__ __forceinline__ void pack4(ushort_t* dst, float x0, float x1,
                                      float x2, float x3) {
  uint2 v;
  v.x = f2bf_u(x0) | (f2bf_u(x1) << 16);
  v.y = f2bf_u(x2) | (f2bf_u(x3) << 16);
  *(uint2*)dst = v;
}
__device__ __forceinline__ void mlmerge(float& M, float& L, float m2, float l2) {
  float nm = fmaxf(M, m2);
  float ea = (M  <= -1e29f) ? 0.f : __expf(M - nm);
  float eb = (m2 <= -1e29f) ? 0.f : __expf(m2 - nm);
  L = L * ea + l2 * eb;
  M = nm;
}

// ---------------- 1. prep ----------------
__global__ __launch_bounds__(256) void prep_kernel(
    const float* __restrict__ x, const float* __restrict__ shift,
    const float* __restrict__ maa_x,
    float* __restrict__ dxprev, float* __restrict__ z)
{
  const int t = blockIdx.x;
  const int c = threadIdx.x * 4;
  const size_t base = (size_t)t * C_DIM + c;
  const float4 xc = *(const float4*)&x[base];
  const float4 xp = (t == 0) ? *(const float4*)&shift[c]
                             : *(const float4*)&x[base - C_DIM];
  const float4 mx = *(const float4*)&maa_x[c];
  float4 d, zz;
  d.x = xp.x - xc.x; d.y = xp.y - xc.y; d.z = xp.z - xc.z; d.w = xp.w - xc.w;
  zz.x = xc.x + d.x*mx.x; zz.y = xc.y + d.y*mx.y;
  zz.z = xc.z + d.z*mx.z; zz.w = xc.w + d.w*mx.w;
  *(float4*)&dxprev[base] = d;
  *(float4*)&z[base] = zz;
}

// ---------------- 2. lora1: xxx & ha ----------------
__global__ __launch_bounds__(256) void lora1_kernel(
    const float* __restrict__ z, const float* __restrict__ x,
    const float* __restrict__ w1, const float* __restrict__ hw1,
    float* __restrict__ xxx, float* __restrict__ ha)
{
  __shared__ float zr[4][C_DIM];
  __shared__ float xr[4][C_DIM];
  const int t0 = blockIdx.x * 4;
  const int tid = threadIdx.x;
  #pragma unroll
  for (int i = 0; i < 4; i++) {
    const int u = tid + i*256;
    const int r = u >> 8;
    const int cc = (u & 255) * 4;
    *(float4*)&zr[r][cc] = *(const float4*)&z[(size_t)(t0+r)*C_DIM + cc];
    *(float4*)&xr[r][cc] = *(const float4*)&x[(size_t)(t0+r)*C_DIM + cc];
  }
  __syncthreads();
  float a0=0.f, a1=0.f, a2=0.f, a3=0.f;
  if (tid < 96) {
    #pragma unroll 4
    for (int cc = 0; cc < C_DIM; cc++) {
      const float w = w1[(size_t)cc*96 + tid];
      a0 += zr[0][cc]*w; a1 += zr[1][cc]*w; a2 += zr[2][cc]*w; a3 += zr[3][cc]*w;
    }
    xxx[(size_t)(t0+0)*96 + tid] = tanhf(a0);
    xxx[(size_t)(t0+1)*96 + tid] = tanhf(a1);
    xxx[(size_t)(t0+2)*96 + tid] = tanhf(a2);
    xxx[(size_t)(t0+3)*96 + tid] = tanhf(a3);
  } else if (tid < 224) {
    const int j = tid - 96;
    #pragma unroll 4
    for (int cc = 0; cc < C_DIM; cc++) {
      const float w = hw1[(size_t)cc*128 + j];
      a0 += xr[0][cc]*w; a1 += xr[1][cc]*w; a2 += xr[2][cc]*w; a3 += xr[3][cc]*w;
    }
    ha[(size_t)(t0+0)*128 + j] = tanhf(a0);
    ha[(size_t)(t0+1)*128 + j] = tanhf(a1);
    ha[(size_t)(t0+2)*128 + j] = tanhf(a2);
    ha[(size_t)(t0+3)*128 + j] = tanhf(a3);
  }
}

// ---------------- 3. mix: xq/xk/xv (bf16 out) ----------------
__global__ __launch_bounds__(256) void mix_kernel(
    const float* __restrict__ x, const float* __restrict__ dxp,
    const float* __restrict__ xxx,
    const float* __restrict__ maa_r, const float* __restrict__ maa_k,
    const float* __restrict__ maa_v, const float* __restrict__ w2,
    ushort_t* __restrict__ xq, ushort_t* __restrict__ xk,
    ushort_t* __restrict__ xv)
{
  __shared__ float xs[96];
  const int t = blockIdx.x;
  const int tid = threadIdx.x;
  if (tid < 96) xs[tid] = xxx[(size_t)t*96 + tid];
  __syncthreads();
  const int c = tid * 4;
  const size_t base = (size_t)t*C_DIM + c;
  const float4 xc = *(const float4*)&x[base];
  const float4 dx = *(const float4*)&dxp[base];
  const float* maas[3] = {maa_r, maa_k, maa_v};
  ushort_t* outs[3] = {xq, xk, xv};
  #pragma unroll
  for (int n = 0; n < 3; n++) {
    const float4 mv = *(const float4*)&maas[n][c];
    float m0 = mv.x, m1 = mv.y, m2 = mv.z, m3 = mv.w;
    #pragma unroll 8
    for (int d = 0; d < 32; d++) {
      const float xval = xs[n*32 + d];
      const float4 w = *(const float4*)&w2[((size_t)n*32 + d)*C_DIM + c];
      m0 += xval*w.x; m1 += xval*w.y; m2 += xval*w.z; m3 += xval*w.w;
    }
    pack4(&outs[n][base], xc.x + dx.x*m0, xc.y + dx.y*m1,
          xc.z + dx.z*m2, xc.w + dx.w*m3);
  }
}

// ---------------- 4. hm ----------------
__global__ __launch_bounds__(256) void hm_kernel(
    const float* __restrict__ ha, const float* __restrict__ hw2,
    float* __restrict__ hm, int T)
{
  const int t = blockIdx.x*4 + (threadIdx.x >> 6);
  const int u = threadIdx.x & 63;
  const int n = u >> 4, h = u & 15;
  float s = 0.f;
  #pragma unroll 8
  for (int d = 0; d < 32; d++)
    s += ha[(size_t)t*128 + n*32 + d] * hw2[(size_t)(n*32 + d)*16 + h];
  hm[((size_t)n*T + t)*16 + h] = s * (1.f/16.f);
}

// ---------------- 5. weight prep: W[k][n] f32 -> Wt[n][k] bf16 ----------------
__global__ __launch_bounds__(256) void wprep_kernel(
    const float* __restrict__ w0, const float* __restrict__ w1,
    const float* __restrict__ w2, const float* __restrict__ w3,
    ushort_t* __restrict__ o0, ushort_t* __restrict__ o1,
    ushort_t* __restrict__ o2, ushort_t* __restrict__ o3)
{
  const float* W; ushort_t* O;
  if (blockIdx.z == 0)      { W = w0; O = o0; }
  else if (blockIdx.z == 1) { W = w1; O = o1; }
  else if (blockIdx.z == 2) { W = w2; O = o2; }
  else                      { W = w3; O = o3; }
  __shared__ float tile[32][33];
  const int k0 = blockIdx.x*32, n0 = blockIdx.y*32;
  const int r = threadIdx.x >> 3, c4 = (threadIdx.x & 7) * 4;
  const float4 v = *(const float4*)&W[(size_t)(k0+r)*C_DIM + n0 + c4];
  tile[r][c4+0] = v.x; tile[r][c4+1] = v.y;
  tile[r][c4+2] = v.z; tile[r][c4+3] = v.w;
  __syncthreads();
  pack4(&O[(size_t)(n0+r)*C_DIM + k0 + c4],
        tile[c4+0][r], tile[c4+1][r], tile[c4+2][r], tile[c4+3][r]);
}

// ---------------- 6. bf16 MFMA GEMM: C[M,N] = A[M,K] @ Bt[N,K]^T ----------------
// 1 wave per block, 32(m) x 64(n) tile, direct global frag loads (L2-resident).
__global__ __launch_bounds__(64) void gemm_bf16(
    const ushort_t* __restrict__ A, const ushort_t* __restrict__ Bt,
    float* __restrict__ Cm, int M, int N, int K)
{
  const int bm = blockIdx.x * 32;
  const int bn = blockIdx.y * 64;
  const int lane = threadIdx.x;
  const int l15 = lane & 15, g = lane >> 4;
  f32x4 acc[2][4];
  #pragma unroll
  for (int i = 0; i < 2; i++)
    #pragma unroll
    for (int j = 0; j < 4; j++) acc[i][j] = (f32x4){0.f,0.f,0.f,0.f};
  #pragma unroll 2
  for (int k0 = 0; k0 < K; k0 += 32) {
    bf16x8 af[2], bfr[4];
    #pragma unroll
    for (int i = 0; i < 2; i++)
      af[i] = *(const bf16x8*)&A[(size_t)(bm + i*16 + l15)*K + k0 + g*8];
    #pragma unroll
    for (int j = 0; j < 4; j++)
      bfr[j] = *(const bf16x8*)&Bt[(size_t)(bn + j*16 + l15)*K + k0 + g*8];
    #pragma unroll
    for (int i = 0; i < 2; i++)
      #pragma unroll
      for (int j = 0; j < 4; j++)
        acc[i][j] = MFMA16(af[i], bfr[j], acc[i][j]);
  }
  #pragma unroll
  for (int i = 0; i < 2; i++)
    #pragma unroll
    for (int j = 0; j < 4; j++)
      #pragma unroll
      for (int r = 0; r < 4; r++)
        Cm[(size_t)(bm + i*16 + g*4 + r)*N + bn + j*16 + l15] = acc[i][j][r];
}

// ---------------- 7. row LayerNorm (optional bf16 out, optional scale) --------
template<int OUT_BF16>
__global__ __launch_bounds__(256) void ln_rows(
    const float* __restrict__ in, void* __restrict__ outp,
    const float* __restrict__ g, const float* __restrict__ b, float scale)
{
  __shared__ float red[4];
  const int t = blockIdx.x;
  const int tid = threadIdx.x;
  const int c = tid*4;
  const float4 v = *(const float4*)&in[(size_t)t*C_DIM + c];
  float s = v.x+v.y+v.z+v.w;
  #pragma unroll
  for (int off = 32; off > 0; off >>= 1) s += __shfl_down(s, off, 64);
  if ((tid & 63) == 0) red[tid >> 6] = s;
  __syncthreads();
  const float mean = (red[0]+red[1]+red[2]+red[3]) * (1.0f/C_DIM);
  __syncthreads();
  const float d0 = v.x-mean, d1 = v.y-mean, d2 = v.z-mean, d3 = v.w-mean;
  float q = d0*d0 + d1*d1 + d2*d2 + d3*d3;
  #pragma unroll
  for (int off = 32; off > 0; off >>= 1) q += __shfl_down(q, off, 64);
  if ((tid & 63) == 0) red[tid >> 6] = q;
  __syncthreads();
  const float var = (red[0]+red[1]+red[2]+red[3]) * (1.0f/C_DIM);
  const float rstd = rsqrtf(var + 1e-5f);
  const float4 gv = *(const float4*)&g[c];
  const float4 bv = *(const float4*)&b[c];
  const float o0 = (d0*rstd*gv.x + bv.x) * scale;
  const float o1 = (d1*rstd*gv.y + bv.y) * scale;
  const float o2 = (d2*rstd*gv.z + bv.z) * scale;
  const float o3 = (d3*rstd*gv.w + bv.w) * scale;
  if (OUT_BF16) {
    pack4((ushort_t*)outp + (size_t)t*C_DIM + c, o0, o1, o2, o3);
  } else {
    *(float4*)((float*)outp + (size_t)t*C_DIM + c) = make_float4(o0,o1,o2,o3);
  }
}

// ---------------- 8. V transpose: vbf[T][1024] -> Vt[1024][T] ----------------
__global__ __launch_bounds__(256) void vtrans_kernel(
    const ushort_t* __restrict__ vbf, ushort_t* __restrict__ Vt, int T)
{
  __shared__ ushort_t tile[32][36];
  const int t0 = blockIdx.x*32, c0 = blockIdx.y*32;
  const int r = threadIdx.x >> 3, c4 = (threadIdx.x & 7) * 4;
  const uint2 raw = *(const uint2*)&vbf[(size_t)(t0+r)*C_DIM + c0 + c4];
  tile[r][c4+0] = (ushort_t)(raw.x & 0xffffu);
  tile[r][c4+1] = (ushort_t)(raw.x >> 16);
  tile[r][c4+2] = (ushort_t)(raw.y & 0xffffu);
  tile[r][c4+3] = (ushort_t)(raw.y >> 16);
  __syncthreads();
  uint2 w;
  w.x = (unsigned)tile[c4+0][r] | ((unsigned)tile[c4+1][r] << 16);
  w.y = (unsigned)tile[c4+2][r] | ((unsigned)tile[c4+3][r] << 16);
  *(uint2*)&Vt[(size_t)(c0+r)*T + t0 + c4] = w;
}

// ---------------- 9. attention phase A: softmax stats ----------------
// grid (T/32, 8); 1024 threads = 16 waves; wave = head.
__global__ __launch_bounds__(1024) void attn_stats(
    const ushort_t* __restrict__ qbf, const ushort_t* __restrict__ kbf,
    const float* __restrict__ hmb, float* __restrict__ part_m,
    float* __restrict__ part_l, int T)
{
  __shared__ ushort_t ybuf[HEADS*TTL*PADS];
  __shared__ float ep[TTL*EPS_STR];

  const int tb = (int)gridDim.x - 1 - (int)blockIdx.x;
  const int sc = blockIdx.y;
  const int t0 = tb * TTL;
  const int sbeg = sc * SCHUNK;
  if (sbeg >= t0 + TTL) return;
  const int send = (sbeg + SCHUNK < t0 + TTL) ? (sbeg + SCHUNK) : (t0 + TTL);

  const int tid = threadIdx.x;
  const int h = tid >> 6;
  const int lane = tid & 63;
  const int l15 = lane & 15, g = lane >> 4;
  const int tc = tid >> 5, scell = tid & 31;   // e-buffer cell ownership

  bf16x8 qf[2][2];
  #pragma unroll
  for (int th = 0; th < 2; th++)
    #pragma unroll
    for (int kc = 0; kc < 2; kc++)
      qf[th][kc] = *(const bf16x8*)
          &qbf[(size_t)(t0 + th*16 + l15)*C_DIM + h*64 + kc*32 + g*8];
  const float slope = exp2f(-0.5f * (float)(h + 1));
  float mrun[2] = {-1e30f, -1e30f}, lrun[2] = {0.f, 0.f};

  for (int s1 = sbeg; s1 < send; s1 += STL) {
    f32x4 acc[2][2];
    #pragma unroll
    for (int sh = 0; sh < 2; sh++)
      #pragma unroll
      for (int th = 0; th < 2; th++) acc[sh][th] = (f32x4){0.f,0.f,0.f,0.f};
    #pragma unroll
    for (int sh = 0; sh < 2; sh++)
      #pragma unroll
      for (int kc = 0; kc < 2; kc++) {
        const bf16x8 kf = *(const bf16x8*)
            &kbf[(size_t)(s1 + sh*16 + l15)*C_DIM + h*64 + kc*32 + g*8];
        #pragma unroll
        for (int th = 0; th < 2; th++)
          acc[sh][th] = MFMA16(kf, qf[th][kc], acc[sh][th]);
      }
    // write y0 (q pre-scaled -> acc is final scaled scores)
    #pragma unroll
    for (int sh = 0; sh < 2; sh++)
      #pragma unroll
      for (int th = 0; th < 2; th++)
        pack4(&ybuf[(h*TTL + th*16 + l15)*PADS + sh*16 + g*4],
              acc[sh][th][0], acc[sh][th][1], acc[sh][th][2], acc[sh][th][3]);
    __syncthreads();
    {  // e_pre for cell (tc, scell)
      float hq[16], hk[16];
      *(float4*)&hq[0]  = *(const float4*)&hmb[((size_t)0*T + t0+tc)*16];
      *(float4*)&hq[4]  = *(const float4*)&hmb[((size_t)0*T + t0+tc)*16 + 4];
      *(float4*)&hq[8]  = *(const float4*)&hmb[((size_t)0*T + t0+tc)*16 + 8];
      *(float4*)&hq[12] = *(const float4*)&hmb[((size_t)0*T + t0+tc)*16 + 12];
      *(float4*)&hk[0]  = *(const float4*)&hmb[((size_t)1*T + s1+scell)*16];
      *(float4*)&hk[4]  = *(const float4*)&hmb[((size_t)1*T + s1+scell)*16 + 4];
      *(float4*)&hk[8]  = *(const float4*)&hmb[((size_t)1*T + s1+scell)*16 + 8];
      *(float4*)&hk[12] = *(const float4*)&hmb[((size_t)1*T + s1+scell)*16 + 12];
      float a = 0.f, b0 = 0.f, spk = 0.f;
      #pragma unroll
      for (int h2 = 0; h2 < 16; h2++) {
        const float y = bf2f(ybuf[(h2*TTL + tc)*PADS + scell]);
        a += y * hq[h2];
        b0 += y * hk[h2];
        spk += hk[h2];
      }
      ep[tc*EPS_STR + scell] = a*(1.f + spk) + b0;
    }
    __syncthreads();
    // online stats from y3
    #pragma unroll
    for (int th = 0; th < 2; th++) {
      const int t = t0 + th*16 + l15;
      #pragma unroll
      for (int sh = 0; sh < 2; sh++)
        #pragma unroll
        for (int r = 0; r < 4; r++) {
          const int s = s1 + sh*16 + g*4 + r;
          if (s <= t) {
            const float y3 = acc[sh][th][r]
                + ep[(th*16 + l15)*EPS_STR + sh*16 + g*4 + r]
                - slope * (float)(t - s);
            const float d = y3 - mrun[th];
            if (d > 0.f) { lrun[th] = lrun[th]*__expf(-d) + 1.f; mrun[th] = y3; }
            else lrun[th] += __expf(d);
          }
        }
    }
    __syncthreads();
  }
  // reduce across the 4 lane-groups (same t, different s-subsets)
  #pragma unroll
  for (int th = 0; th < 2; th++) {
    float M = mrun[th], L = lrun[th];
    #pragma unroll
    for (int mask = 16; mask < 64; mask <<= 1) {
      const float M2 = __shfl_xor(M, mask, 64);
      const float L2 = __shfl_xor(L, mask, 64);
      mlmerge(M, L, M2, L2);
    }
    if (g == 0) {
      part_m[(size_t)(sc*HEADS + h)*T + t0 + th*16 + l15] = M;
      part_l[(size_t)(sc*HEADS + h)*T + t0 + th*16 + l15] = L;
    }
  }
}

// ---------------- 10. merge partial (m,l) ----------------
__global__ __launch_bounds__(256) void ml_combine(
    const float* __restrict__ part_m, const float* __restrict__ part_l,
    float* __restrict__ m_fin, float* __restrict__ linv, int T)
{
  const int idx = blockIdx.x*256 + threadIdx.x;   // h*T + t
  const int t = idx & (T - 1);
  const int t0 = t & ~(TTL - 1);
  const int nsc = (t0 + TTL + SCHUNK - 1) / SCHUNK;
  float M = -1e30f, L = 0.f;
  for (int sc = 0; sc < nsc; sc++)
    mlmerge(M, L, part_m[(size_t)sc*HEADS*T + idx],
            part_l[(size_t)sc*HEADS*T + idx]);
  m_fin[idx] = M;
  linv[idx] = 1.f / L;
}

// ---------------- 11. attention phase B: apply ----------------
__global__ __launch_bounds__(1024) void attn_apply(
    const ushort_t* __restrict__ qbf, const ushort_t* __restrict__ kbf,
    const ushort_t* __restrict__ Vt, const float* __restrict__ hmb,
    const float* __restrict__ m_fin, const float* __restrict__ linv,
    float* __restrict__ out, int T)
{
  __shared__ ushort_t ybuf[HEADS*TTL*PADS];
  __shared__ float ep[TTL*EPS_STR];

  const int tb = (int)gridDim.x - 1 - (int)blockIdx.x;
  const int sc = blockIdx.y;
  const int t0 = tb * TTL;
  const int sbeg = sc * SCHUNK;
  if (sbeg >= t0 + TTL) return;
  const int send = (sbeg + SCHUNK < t0 + TTL) ? (sbeg + SCHUNK) : (t0 + TTL);

  const int tid = threadIdx.x;
  const int h = tid >> 6;
  const int lane = tid & 63;
  const int l15 = lane & 15, g = lane >> 4;
  const int tc = tid >> 5, scell = tid & 31;

  bf16x8 qf[2][2];
  float mt[2], li[2];
  #pragma unroll
  for (int th = 0; th < 2; th++) {
    #pragma unroll
    for (int kc = 0; kc < 2; kc++)
      qf[th][kc] = *(const bf16x8*)
          &qbf[(size_t)(t0 + th*16 + l15)*C_DIM + h*64 + kc*32 + g*8];
    mt[th] = m_fin[(size_t)h*T + t0 + th*16 + l15];
    li[th] = linv[(size_t)h*T + t0 + th*16 + l15];
  }
  const float slope = exp2f(-0.5f * (float)(h + 1));
  f32x4 oacc[2][4];
  #pragma unroll
  for (int th = 0; th < 2; th++)
    #pragma unroll
    for (int vf = 0; vf < 4; vf++) oacc[th][vf] = (f32x4){0.f,0.f,0.f,0.f};

  for (int s1 = sbeg; s1 < send; s1 += STL) {
    f32x4 acc[2][2];
    #pragma unroll
    for (int sh = 0; sh < 2; sh++)
      #pragma unroll
      for (int th = 0; th < 2; th++) acc[sh][th] = (f32x4){0.f,0.f,0.f,0.f};
    #pragma unroll
    for (int sh = 0; sh < 2; sh++)
      #pragma unroll
      for (int kc = 0; kc < 2; kc++) {
        const bf16x8 kf = *(const bf16x8*)
            &kbf[(size_t)(s1 + sh*16 + l15)*C_DIM + h*64 + kc*32 + g*8];
        #pragma unroll
        for (int th = 0; th < 2; th++)
          acc[sh][th] = MFMA16(kf, qf[th][kc], acc[sh][th]);
      }
    #pragma unroll
    for (int sh = 0; sh < 2; sh++)
      #pragma unroll
      for (int th = 0; th < 2; th++)
        pack4(&ybuf[(h*TTL + th*16 + l15)*PADS + sh*16 + g*4],
              acc[sh][th][0], acc[sh][th][1], acc[sh][th][2], acc[sh][th][3]);
    __syncthreads();
    {  // e_pre
      float hq[16], hk[16];
      #pragma unroll
      for (int q4 = 0; q4 < 4; q4++) {
        *(float4*)&hq[q4*4] = *(const float4*)&hmb[((size_t)0*T + t0+tc)*16 + q4*4];
        *(float4*)&hk[q4*4] = *(const float4*)&hmb[((size_t)1*T + s1+scell)*16 + q4*4];
      }
      float a = 0.f, b0 = 0.f, spk = 0.f;
      #pragma unroll
      for (int h2 = 0; h2 < 16; h2++) {
        const float y = bf2f(ybuf[(h2*TTL + tc)*PADS + scell]);
        a += y * hq[h2];
        b0 += y * hk[h2];
        spk += hk[h2];
      }
      ep[tc*EPS_STR + scell] = a*(1.f + spk) + b0;
    }
    __syncthreads();
    // p = exp(y3 - m) * inv_l  (0 if masked); keep p in acc regs
    #pragma unroll
    for (int th = 0; th < 2; th++) {
      const int t = t0 + th*16 + l15;
      #pragma unroll
      for (int sh = 0; sh < 2; sh++)
        #pragma unroll
        for (int r = 0; r < 4; r++) {
          const int s = s1 + sh*16 + g*4 + r;
          float p = 0.f;
          if (s <= t) {
            const float y3 = acc[sh][th][r]
                + ep[(th*16 + l15)*EPS_STR + sh*16 + g*4 + r]
                - slope * (float)(t - s);
            p = __expf(y3 - mt[th]) * li[th];
          }
          acc[sh][th][r] = p;
        }
    }
    #pragma unroll
    for (int sh = 0; sh < 2; sh++)
      #pragma unroll
      for (int th = 0; th < 2; th++)
        pack4(&ybuf[(h*TTL + th*16 + l15)*PADS + sh*16 + g*4],
              acc[sh][th][0], acc[sh][th][1], acc[sh][th][2], acc[sh][th][3]);
    __syncthreads();
    {  // e_post (reuse ep; separated from step-p reads by the barrier above)
      float hq[16], hk[16];
      #pragma unroll
      for (int q4 = 0; q4 < 4; q4++) {
        *(float4*)&hq[q4*4] = *(const float4*)&hmb[((size_t)2*T + t0+tc)*16 + q4*4];
        *(float4*)&hk[q4*4] = *(const float4*)&hmb[((size_t)3*T + s1+scell)*16 + q4*4];
      }
      float cmx = 0.f, d0 = 0.f, spo = 0.f;
      #pragma unroll
      for (int h2 = 0; h2 < 16; h2++) {
        const float p = bf2f(ybuf[(h2*TTL + tc)*PADS + scell]);
        cmx += p * hq[h2];
        d0 += p * hk[h2];
        spo += hk[h2];
      }
      ep[tc*EPS_STR + scell] = cmx*(1.f + spo) + d0;
    }
    __syncthreads();
    // p2 = p + e_post
    #pragma unroll
    for (int sh = 0; sh < 2; sh++)
      #pragma unroll
      for (int th = 0; th < 2; th++) {
        const int ebase = (th*16 + l15)*EPS_STR + sh*16 + g*4;
        pack4(&ybuf[(h*TTL + th*16 + l15)*PADS + sh*16 + g*4],
              acc[sh][th][0] + ep[ebase+0], acc[sh][th][1] + ep[ebase+1],
              acc[sh][th][2] + ep[ebase+2], acc[sh][th][3] + ep[ebase+3]);
      }
    __syncthreads();
    // PV: out[t][v] += P2[t][s] * V[s][v]   (Vt[c][s] global, L2-resident)
    #pragma unroll
    for (int th = 0; th < 2; th++) {
      const bf16x8 pa = *(const bf16x8*)&ybuf[(h*TTL + th*16 + l15)*PADS + g*8];
      #pragma unroll
      for (int vf = 0; vf < 4; vf++) {
        const bf16x8 vv = *(const bf16x8*)
            &Vt[(size_t)(h*64 + vf*16 + l15)*T + s1 + g*8];
        oacc[th][vf] = MFMA16(pa, vv, oacc[th][vf]);
      }
    }
    __syncthreads();
  }
  #pragma unroll
  for (int th = 0; th < 2; th++)
    #pragma unroll
    for (int vf = 0; vf < 4; vf++)
      #pragma unroll
      for (int r = 0; r < 4; r++)
        atomicAdd(&out[(size_t)(t0 + th*16 + g*4 + r)*C_DIM
                       + h*64 + vf*16 + l15], oacc[th][vf][r]);
}

// ---------------- launcher ----------------
extern "C" void kernel_launch(void* const* d_in, const int* in_sizes, int n_in,
                              void* d_out, int out_size, void* d_ws, size_t ws_size,
                              hipStream_t stream)
{
  const float* x      = (const float*)d_in[0];
  const float* shift  = (const float*)d_in[1];
  const float* maa_x  = (const float*)d_in[2];
  const float* maa_r  = (const float*)d_in[3];
  const float* maa_k  = (const float*)d_in[4];
  const float* maa_v  = (const float*)d_in[5];
  const float* w1     = (const float*)d_in[6];
  const float* w2     = (const float*)d_in[7];
  const float* hw1    = (const float*)d_in[8];
  const float* hw2    = (const float*)d_in[9];
  const float* w_r    = (const float*)d_in[10];
  const float* w_k    = (const float*)d_in[11];
  const float* w_v    = (const float*)d_in[12];
  const float* w_o    = (const float*)d_in[13];
  const float* ln_r_g = (const float*)d_in[14];
  const float* ln_r_b = (const float*)d_in[15];
  const float* ln_k_g = (const float*)d_in[16];
  const float* ln_k_b = (const float*)d_in[17];
  const float* ln_v_g = (const float*)d_in[18];
  const float* ln_v_b = (const float*)d_in[19];
  const float* ln_x_g = (const float*)d_in[20];
  const float* ln_x_b = (const float*)d_in[21];

  const int T = in_sizes[0] / C_DIM;            // 2048
  const size_t MM = (size_t)T * C_DIM;          // 2M elems
  const size_t HF = MM / 2;                     // bf16 tensor size in float units

  float* ws = (float*)d_ws;
  float* dxprev   = ws;                  // f32 [T][C]   (later: attn_out)
  float* zbuf     = ws + MM;             // f32 [T][C]   (later: abf bf16)
  float* b16base  = ws + 2*MM;
  ushort_t* xqb = (ushort_t*)(b16base + 0*HF);
  ushort_t* xkb = (ushort_t*)(b16base + 1*HF);
  ushort_t* xvb = (ushort_t*)(b16base + 2*HF);
  ushort_t* qbf = (ushort_t*)(b16base + 3*HF);
  ushort_t* kbf = (ushort_t*)(b16base + 4*HF);
  ushort_t* vbf = (ushort_t*)(b16base + 5*HF);
  ushort_t* Vt  = (ushort_t*)(b16base + 6*HF);          // [1024][T]
  ushort_t* wtr = (ushort_t*)(b16base + 8*HF);          // 4 x [1024][1024]
  ushort_t* wtk = wtr + (size_t)C_DIM*C_DIM;
  ushort_t* wtv = wtk + (size_t)C_DIM*C_DIM;
  ushort_t* wto = wtv + (size_t)C_DIM*C_DIM;
  float* smalls = b16base + 8*HF + 2*MM;        // after weights (4*1M*2B = 2M fl)
  float* xxx    = smalls;                        // T*96
  float* ha     = xxx + (size_t)T*96;            // T*128
  float* hmb    = ha + (size_t)T*128;            // 4*T*16
  float* part_m = hmb + (size_t)4*T*16;          // 8*16*T
  float* part_l = part_m + (size_t)8*16*T;       // 8*16*T
  float* m_fin  = part_l + (size_t)8*16*T;       // 16*T
  float* linv   = m_fin + (size_t)16*T;          // 16*T

  float* attn_out = dxprev;
  ushort_t* abf = (ushort_t*)zbuf;

  prep_kernel<<<T, 256, 0, stream>>>(x, shift, maa_x, dxprev, zbuf);
  lora1_kernel<<<T/4, 256, 0, stream>>>(zbuf, x, w1, hw1, xxx, ha);
  mix_kernel<<<T, 256, 0, stream>>>(x, dxprev, xxx, maa_r, maa_k, maa_v, w2,
                                    xqb, xkb, xvb);
  hm_kernel<<<T/4, 256, 0, stream>>>(ha, hw2, hmb, T);
  wprep_kernel<<<dim3(32, 32, 4), 256, 0, stream>>>(
      w_r, w_k, w_v, w_o, wtr, wtk, wtv, wto);

  const dim3 gg(T/32, C_DIM/64);
  gemm_bf16<<<gg, 64, 0, stream>>>(xqb, wtr, zbuf, T, C_DIM, C_DIM);
  ln_rows<1><<<T, 256, 0, stream>>>(zbuf, qbf, ln_r_g, ln_r_b, 0.125f);
  gemm_bf16<<<gg, 64, 0, stream>>>(xkb, wtk, zbuf, T, C_DIM, C_DIM);
  ln_rows<1><<<T, 256, 0, stream>>>(zbuf, kbf, ln_k_g, ln_k_b, 1.0f);
  gemm_bf16<<<gg, 64, 0, stream>>>(xvb, wtv, zbuf, T, C_DIM, C_DIM);
  ln_rows<1><<<T, 256, 0, stream>>>(zbuf, vbf, ln_v_g, ln_v_b, 1.0f);
  vtrans_kernel<<<dim3(T/32, C_DIM/32), 256, 0, stream>>>(vbf, Vt, T);

  hipMemsetAsync(attn_out, 0, MM*sizeof(float), stream);
  attn_stats<<<dim3(T/TTL, 8), 1024, 0, stream>>>(
      qbf, kbf, hmb, part_m, part_l, T);
  ml_combine<<<(HEADS*T)/256, 256, 0, stream>>>(part_m, part_l, m_fin, linv, T);
  attn_apply<<<dim3(T/TTL, 8), 1024, 0, stream>>>(
      qbf, kbf, Vt, hmb, m_fin, linv, attn_out, T);

  ln_rows<1><<<T, 256, 0, stream>>>(attn_out, abf, ln_x_g, ln_x_b, 1.0f);
  gemm_bf16<<<gg, 64, 0, stream>>>(abf, wto, (float*)d_out, T, C_DIM, C_DIM);
}

// Round 4
// 572.149 us; speedup vs baseline: 3.7520x; 1.1958x over previous
//
#include <hip/hip_runtime.h>
#include <cstdint>
#include <cstddef>

// RWKV_Tmix_headmixer — round 4: round-3 structure with the workspace-layout
// fix (weights occupy 2*C*C f32 units, not C*C).
// B=1, T=2048, C=1024, H=16, K=64.

#define C_DIM 1024
#define HEADS 16
#define TTL 32
#define STL 32
#define SCHUNK 256
#define PADS 40          // ybuf inner stride (bf16) -> conflict-free reads
#define EPS_STR 36       // e_pre/e_post f32 stride

typedef unsigned short ushort_t;
typedef __attribute__((ext_vector_type(8))) short bf16x8;
typedef __attribute__((ext_vector_type(4))) float f32x4;

#define MFMA16(a, b, c) __builtin_amdgcn_mfma_f32_16x16x32_bf16(a, b, c, 0, 0, 0)

__device__ __forceinline__ unsigned int f2bf_u(float f) {
  unsigned int u = __float_as_uint(f);
  return (u + 0x7fffu + ((u >> 16) & 1u)) >> 16;   // RNE
}
__device__ __forceinline__ float bf2f(ushort_t u) {
  return __uint_as_float(((unsigned int)u) << 16);
}
__device__ __forceinline__ void pack4(ushort_t* dst, float x0, float x1,
                                      float x2, float x3) {
  uint2 v;
  v.x = f2bf_u(x0) | (f2bf_u(x1) << 16);
  v.y = f2bf_u(x2) | (f2bf_u(x3) << 16);
  *(uint2*)dst = v;
}
__device__ __forceinline__ void mlmerge(float& M, float& L, float m2, float l2) {
  float nm = fmaxf(M, m2);
  float ea = (M  <= -1e29f) ? 0.f : __expf(M - nm);
  float eb = (m2 <= -1e29f) ? 0.f : __expf(m2 - nm);
  L = L * ea + l2 * eb;
  M = nm;
}

// ---------------- 1. prep: dxprev f32, z & x copies in bf16 ----------------
__global__ __launch_bounds__(256) void prep_kernel(
    const float* __restrict__ x, const float* __restrict__ shift,
    const float* __restrict__ maa_x,
    float* __restrict__ dxprev, ushort_t* __restrict__ zbf,
    ushort_t* __restrict__ xbf)
{
  const int t = blockIdx.x;
  const int c = threadIdx.x * 4;
  const size_t base = (size_t)t * C_DIM + c;
  const float4 xc = *(const float4*)&x[base];
  const float4 xp = (t == 0) ? *(const float4*)&shift[c]
                             : *(const float4*)&x[base - C_DIM];
  const float4 mx = *(const float4*)&maa_x[c];
  float4 d;
  d.x = xp.x - xc.x; d.y = xp.y - xc.y; d.z = xp.z - xc.z; d.w = xp.w - xc.w;
  *(float4*)&dxprev[base] = d;
  pack4(&zbf[base], xc.x + d.x*mx.x, xc.y + d.y*mx.y,
        xc.z + d.z*mx.z, xc.w + d.w*mx.w);
  pack4(&xbf[base], xc.x, xc.y, xc.z, xc.w);
}

// ---------------- 2. lora weight prep: w1[1024,96]++hw1[1024,128] -> wlt[224][1024]
__global__ __launch_bounds__(256) void wlora_prep(
    const float* __restrict__ w1, const float* __restrict__ hw1,
    ushort_t* __restrict__ wlt)
{
  __shared__ float tile[32][33];
  const int k0 = blockIdx.x*32, j0 = blockIdx.y*32;
  const int r = threadIdx.x >> 3, c4 = (threadIdx.x & 7) * 4;
  const float* W = (j0 < 96) ? w1 : hw1;
  const int stride = (j0 < 96) ? 96 : 128;
  const int jo = (j0 < 96) ? j0 : j0 - 96;
  const float4 v = *(const float4*)&W[(size_t)(k0+r)*stride + jo + c4];
  tile[r][c4+0] = v.x; tile[r][c4+1] = v.y;
  tile[r][c4+2] = v.z; tile[r][c4+3] = v.w;
  __syncthreads();
  pack4(&wlt[(size_t)(j0+r)*C_DIM + k0 + c4],
        tile[c4+0][r], tile[c4+1][r], tile[c4+2][r], tile[c4+3][r]);
}

// ---------------- 3. lora GEMM with tanh epilogue ----------------
// grid (T/32, 7), 64 thr. nt<3: xxx[t][nt*32+..] = tanh(z@w1); else ha = tanh(x@hw1)
__global__ __launch_bounds__(64) void lora_gemm(
    const ushort_t* __restrict__ zbf, const ushort_t* __restrict__ xbf,
    const ushort_t* __restrict__ wlt, float* __restrict__ xxx,
    float* __restrict__ ha)
{
  const int nt = blockIdx.y;
  const int bm = blockIdx.x * 32;
  const ushort_t* A = (nt < 3) ? zbf : xbf;
  const int wrow = nt * 32;
  const int lane = threadIdx.x;
  const int l15 = lane & 15, g = lane >> 4;
  f32x4 acc[2][2];
  #pragma unroll
  for (int i = 0; i < 2; i++)
    #pragma unroll
    for (int j = 0; j < 2; j++) acc[i][j] = (f32x4){0.f,0.f,0.f,0.f};
  bf16x8 a0[2], b0[2], a1[2], b1[2];
  #define LLA(dst, kk) { \
    dst[0] = *(const bf16x8*)&A[(size_t)(bm + l15)*C_DIM + (kk) + g*8]; \
    dst[1] = *(const bf16x8*)&A[(size_t)(bm + 16 + l15)*C_DIM + (kk) + g*8]; }
  #define LLB(dst, kk) { \
    dst[0] = *(const bf16x8*)&wlt[(size_t)(wrow + l15)*C_DIM + (kk) + g*8]; \
    dst[1] = *(const bf16x8*)&wlt[(size_t)(wrow + 16 + l15)*C_DIM + (kk) + g*8]; }
  LLA(a0, 0); LLB(b0, 0);
  for (int k0 = 0; k0 < C_DIM; k0 += 64) {
    LLA(a1, k0+32); LLB(b1, k0+32);
    #pragma unroll
    for (int i = 0; i < 2; i++)
      #pragma unroll
      for (int j = 0; j < 2; j++) acc[i][j] = MFMA16(a0[i], b0[j], acc[i][j]);
    if (k0 + 64 < C_DIM) { LLA(a0, k0+64); LLB(b0, k0+64); }
    #pragma unroll
    for (int i = 0; i < 2; i++)
      #pragma unroll
      for (int j = 0; j < 2; j++) acc[i][j] = MFMA16(a1[i], b1[j], acc[i][j]);
  }
  #undef LLA
  #undef LLB
  #pragma unroll
  for (int i = 0; i < 2; i++)
    #pragma unroll
    for (int j = 0; j < 2; j++)
      #pragma unroll
      for (int r = 0; r < 4; r++) {
        const int t = bm + i*16 + g*4 + r;
        const int col = wrow + j*16 + l15;
        const float val = tanhf(acc[i][j][r]);
        if (nt < 3) xxx[(size_t)t*96 + col] = val;
        else        ha[(size_t)t*128 + col - 96] = val;
      }
}

// ---------------- 4. mix: xq/xk/xv (bf16), 8 rows/block ----------------
__global__ __launch_bounds__(256) void mix_kernel(
    const float* __restrict__ x, const float* __restrict__ dxp,
    const float* __restrict__ xxx,
    const float* __restrict__ maa_r, const float* __restrict__ maa_k,
    const float* __restrict__ maa_v, const float* __restrict__ w2,
    ushort_t* __restrict__ xq, ushort_t* __restrict__ xk,
    ushort_t* __restrict__ xv)
{
  __shared__ float xs[8][96];
  const int t0 = blockIdx.x * 8;
  const int tid = threadIdx.x;
  #pragma unroll
  for (int i = 0; i < 3; i++) {
    const int u = tid + i*256;
    if (u < 768) {
      const int r = u / 96, cc = u % 96;
      xs[r][cc] = xxx[(size_t)(t0+r)*96 + cc];
    }
  }
  __syncthreads();
  const int c = tid * 4;
  float4 xc[8], dx[8];
  #pragma unroll
  for (int r = 0; r < 8; r++) {
    xc[r] = *(const float4*)&x[(size_t)(t0+r)*C_DIM + c];
    dx[r] = *(const float4*)&dxp[(size_t)(t0+r)*C_DIM + c];
  }
  const float* maas[3] = {maa_r, maa_k, maa_v};
  ushort_t* outs[3] = {xq, xk, xv};
  #pragma unroll
  for (int n = 0; n < 3; n++) {
    const float4 mv = *(const float4*)&maas[n][c];
    float m[8][4];
    #pragma unroll
    for (int r = 0; r < 8; r++) {
      m[r][0] = mv.x; m[r][1] = mv.y; m[r][2] = mv.z; m[r][3] = mv.w;
    }
    #pragma unroll 8
    for (int d = 0; d < 32; d++) {
      const float4 w = *(const float4*)&w2[((size_t)n*32 + d)*C_DIM + c];
      #pragma unroll
      for (int r = 0; r < 8; r++) {
        const float xv2 = xs[r][n*32 + d];
        m[r][0] += xv2*w.x; m[r][1] += xv2*w.y;
        m[r][2] += xv2*w.z; m[r][3] += xv2*w.w;
      }
    }
    #pragma unroll
    for (int r = 0; r < 8; r++)
      pack4(&outs[n][(size_t)(t0+r)*C_DIM + c],
            xc[r].x + dx[r].x*m[r][0], xc[r].y + dx[r].y*m[r][1],
            xc[r].z + dx[r].z*m[r][2], xc[r].w + dx[r].w*m[r][3]);
  }
}

// ---------------- 5. hm ----------------
__global__ __launch_bounds__(256) void hm_kernel(
    const float* __restrict__ ha, const float* __restrict__ hw2,
    float* __restrict__ hm, int T)
{
  const int t = blockIdx.x*4 + (threadIdx.x >> 6);
  const int u = threadIdx.x & 63;
  const int n = u >> 4, h = u & 15;
  float s = 0.f;
  #pragma unroll 8
  for (int d = 0; d < 32; d++)
    s += ha[(size_t)t*128 + n*32 + d] * hw2[(size_t)(n*32 + d)*16 + h];
  hm[((size_t)n*T + t)*16 + h] = s * (1.f/16.f);
}

// ---------------- 6. weight prep: W[k][n] f32 -> Wt[n][k] bf16 ----------------
__global__ __launch_bounds__(256) void wprep_kernel(
    const float* __restrict__ w0, const float* __restrict__ w1,
    const float* __restrict__ w2, const float* __restrict__ w3,
    ushort_t* __restrict__ o0, ushort_t* __restrict__ o1,
    ushort_t* __restrict__ o2, ushort_t* __restrict__ o3)
{
  const float* W; ushort_t* O;
  if (blockIdx.z == 0)      { W = w0; O = o0; }
  else if (blockIdx.z == 1) { W = w1; O = o1; }
  else if (blockIdx.z == 2) { W = w2; O = o2; }
  else                      { W = w3; O = o3; }
  __shared__ float tile[32][33];
  const int k0 = blockIdx.x*32, n0 = blockIdx.y*32;
  const int r = threadIdx.x >> 3, c4 = (threadIdx.x & 7) * 4;
  const float4 v = *(const float4*)&W[(size_t)(k0+r)*C_DIM + n0 + c4];
  tile[r][c4+0] = v.x; tile[r][c4+1] = v.y;
  tile[r][c4+2] = v.z; tile[r][c4+3] = v.w;
  __syncthreads();
  pack4(&O[(size_t)(n0+r)*C_DIM + k0 + c4],
        tile[c4+0][r], tile[c4+1][r], tile[c4+2][r], tile[c4+3][r]);
}

// ---------------- 7. bf16 MFMA GEMM: C[M,1024] = A[M,1024] @ Bt^T -----------
// 1D grid M/32*16; bn-based XCD affinity; depth-1 register double buffer.
__global__ __launch_bounds__(64) void gemm_bf16(
    const ushort_t* __restrict__ A, const ushort_t* __restrict__ Bt,
    float* __restrict__ Cm)
{
  const int bid = blockIdx.x;
  const int bn = (bid & 15) * 64;     // bid%8 tracks bn -> per-XCD B residency
  const int bm = (bid >> 4) * 32;
  const int lane = threadIdx.x;
  const int l15 = lane & 15, g = lane >> 4;
  f32x4 acc[2][4];
  #pragma unroll
  for (int i = 0; i < 2; i++)
    #pragma unroll
    for (int j = 0; j < 4; j++) acc[i][j] = (f32x4){0.f,0.f,0.f,0.f};
  bf16x8 a0[2], b0[4], a1[2], b1[4];
  #define LGA(dst, kk) { \
    _Pragma("unroll") \
    for (int i = 0; i < 2; i++) \
      dst[i] = *(const bf16x8*)&A[(size_t)(bm + i*16 + l15)*C_DIM + (kk) + g*8]; }
  #define LGB(dst, kk) { \
    _Pragma("unroll") \
    for (int j = 0; j < 4; j++) \
      dst[j] = *(const bf16x8*)&Bt[(size_t)(bn + j*16 + l15)*C_DIM + (kk) + g*8]; }
  LGA(a0, 0); LGB(b0, 0);
  for (int k0 = 0; k0 < C_DIM; k0 += 64) {
    LGA(a1, k0+32); LGB(b1, k0+32);
    #pragma unroll
    for (int i = 0; i < 2; i++)
      #pragma unroll
      for (int j = 0; j < 4; j++) acc[i][j] = MFMA16(a0[i], b0[j], acc[i][j]);
    if (k0 + 64 < C_DIM) { LGA(a0, k0+64); LGB(b0, k0+64); }
    #pragma unroll
    for (int i = 0; i < 2; i++)
      #pragma unroll
      for (int j = 0; j < 4; j++) acc[i][j] = MFMA16(a1[i], b1[j], acc[i][j]);
  }
  #undef LGA
  #undef LGB
  #pragma unroll
  for (int i = 0; i < 2; i++)
    #pragma unroll
    for (int j = 0; j < 4; j++)
      #pragma unroll
      for (int r = 0; r < 4; r++)
        Cm[(size_t)(bm + i*16 + g*4 + r)*C_DIM + bn + j*16 + l15] = acc[i][j][r];
}

// ---------------- 8. row LayerNorm -> bf16 ----------------
__global__ __launch_bounds__(256) void ln_rows(
    const float* __restrict__ in, ushort_t* __restrict__ outp,
    const float* __restrict__ g, const float* __restrict__ b, float scale)
{
  __shared__ float red[4];
  const int t = blockIdx.x;
  const int tid = threadIdx.x;
  const int c = tid*4;
  const float4 v = *(const float4*)&in[(size_t)t*C_DIM + c];
  float s = v.x+v.y+v.z+v.w;
  #pragma unroll
  for (int off = 32; off > 0; off >>= 1) s += __shfl_down(s, off, 64);
  if ((tid & 63) == 0) red[tid >> 6] = s;
  __syncthreads();
  const float mean = (red[0]+red[1]+red[2]+red[3]) * (1.0f/C_DIM);
  __syncthreads();
  const float d0 = v.x-mean, d1 = v.y-mean, d2 = v.z-mean, d3 = v.w-mean;
  float q = d0*d0 + d1*d1 + d2*d2 + d3*d3;
  #pragma unroll
  for (int off = 32; off > 0; off >>= 1) q += __shfl_down(q, off, 64);
  if ((tid & 63) == 0) red[tid >> 6] = q;
  __syncthreads();
  const float var = (red[0]+red[1]+red[2]+red[3]) * (1.0f/C_DIM);
  const float rstd = rsqrtf(var + 1e-5f);
  const float4 gv = *(const float4*)&g[c];
  const float4 bv = *(const float4*)&b[c];
  pack4(outp + (size_t)t*C_DIM + c,
        (d0*rstd*gv.x + bv.x)*scale, (d1*rstd*gv.y + bv.y)*scale,
        (d2*rstd*gv.z + bv.z)*scale, (d3*rstd*gv.w + bv.w)*scale);
}

// ---------------- 9. V transpose ----------------
__global__ __launch_bounds__(256) void vtrans_kernel(
    const ushort_t* __restrict__ vbf, ushort_t* __restrict__ Vt, int T)
{
  __shared__ ushort_t tile[32][36];
  const int t0 = blockIdx.x*32, c0 = blockIdx.y*32;
  const int r = threadIdx.x >> 3, c4 = (threadIdx.x & 7) * 4;
  const uint2 raw = *(const uint2*)&vbf[(size_t)(t0+r)*C_DIM + c0 + c4];
  tile[r][c4+0] = (ushort_t)(raw.x & 0xffffu);
  tile[r][c4+1] = (ushort_t)(raw.x >> 16);
  tile[r][c4+2] = (ushort_t)(raw.y & 0xffffu);
  tile[r][c4+3] = (ushort_t)(raw.y >> 16);
  __syncthreads();
  uint2 w;
  w.x = (unsigned)tile[c4+0][r] | ((unsigned)tile[c4+1][r] << 16);
  w.y = (unsigned)tile[c4+2][r] | ((unsigned)tile[c4+3][r] << 16);
  *(uint2*)&Vt[(size_t)(c0+r)*T + t0 + c4] = w;
}

// ---------------- 10. attention phase A: softmax stats ----------------
// 1D grid T/32*8; sc = bid&7 -> XCD-resident K slice.
__global__ __launch_bounds__(1024) void attn_stats(
    const ushort_t* __restrict__ qbf, const ushort_t* __restrict__ kbf,
    const float* __restrict__ hmb, float* __restrict__ part_m,
    float* __restrict__ part_l, int T)
{
  __shared__ ushort_t ybuf[HEADS*TTL*PADS];
  __shared__ float ep[TTL*EPS_STR];

  const int bid = blockIdx.x;
  const int sc = bid & 7;
  const int tb = (T/TTL) - 1 - (bid >> 3);   // longest-first
  const int t0 = tb * TTL;
  const int sbeg = sc * SCHUNK;
  if (sbeg >= t0 + TTL) return;
  const int send = (sbeg + SCHUNK < t0 + TTL) ? (sbeg + SCHUNK) : (t0 + TTL);

  const int tid = threadIdx.x;
  const int h = tid >> 6;
  const int lane = tid & 63;
  const int l15 = lane & 15, g = lane >> 4;
  const int tc = tid >> 5, scell = tid & 31;

  bf16x8 qf[2][2];
  #pragma unroll
  for (int th = 0; th < 2; th++)
    #pragma unroll
    for (int kc = 0; kc < 2; kc++)
      qf[th][kc] = *(const bf16x8*)
          &qbf[(size_t)(t0 + th*16 + l15)*C_DIM + h*64 + kc*32 + g*8];
  const float slope = exp2f(-0.5f * (float)(h + 1));
  float mrun[2] = {-1e30f, -1e30f}, lrun[2] = {0.f, 0.f};

  for (int s1 = sbeg; s1 < send; s1 += STL) {
    f32x4 acc[2][2];
    #pragma unroll
    for (int sh = 0; sh < 2; sh++)
      #pragma unroll
      for (int th = 0; th < 2; th++) acc[sh][th] = (f32x4){0.f,0.f,0.f,0.f};
    #pragma unroll
    for (int sh = 0; sh < 2; sh++)
      #pragma unroll
      for (int kc = 0; kc < 2; kc++) {
        const bf16x8 kf = *(const bf16x8*)
            &kbf[(size_t)(s1 + sh*16 + l15)*C_DIM + h*64 + kc*32 + g*8];
        #pragma unroll
        for (int th = 0; th < 2; th++)
          acc[sh][th] = MFMA16(kf, qf[th][kc], acc[sh][th]);
      }
    #pragma unroll
    for (int sh = 0; sh < 2; sh++)
      #pragma unroll
      for (int th = 0; th < 2; th++)
        pack4(&ybuf[(h*TTL + th*16 + l15)*PADS + sh*16 + g*4],
              acc[sh][th][0], acc[sh][th][1], acc[sh][th][2], acc[sh][th][3]);
    __syncthreads();
    {  // e_pre for cell (tc, scell)
      float hq[16], hk[16];
      #pragma unroll
      for (int q4 = 0; q4 < 4; q4++) {
        *(float4*)&hq[q4*4] = *(const float4*)&hmb[((size_t)0*T + t0+tc)*16 + q4*4];
        *(float4*)&hk[q4*4] = *(const float4*)&hmb[((size_t)1*T + s1+scell)*16 + q4*4];
      }
      float a = 0.f, b0 = 0.f, spk = 0.f;
      #pragma unroll
      for (int h2 = 0; h2 < 16; h2++) {
        const float y = bf2f(ybuf[(h2*TTL + tc)*PADS + scell]);
        a += y * hq[h2];
        b0 += y * hk[h2];
        spk += hk[h2];
      }
      ep[tc*EPS_STR + scell] = a*(1.f + spk) + b0;
    }
    __syncthreads();
    #pragma unroll
    for (int th = 0; th < 2; th++) {
      const int t = t0 + th*16 + l15;
      #pragma unroll
      for (int sh = 0; sh < 2; sh++)
        #pragma unroll
        for (int r = 0; r < 4; r++) {
          const int s = s1 + sh*16 + g*4 + r;
          if (s <= t) {
            const float y3 = acc[sh][th][r]
                + ep[(th*16 + l15)*EPS_STR + sh*16 + g*4 + r]
                - slope * (float)(t - s);
            const float d = y3 - mrun[th];
            if (d > 0.f) { lrun[th] = lrun[th]*__expf(-d) + 1.f; mrun[th] = y3; }
            else lrun[th] += __expf(d);
          }
        }
    }
    __syncthreads();
  }
  #pragma unroll
  for (int th = 0; th < 2; th++) {
    float M = mrun[th], L = lrun[th];
    #pragma unroll
    for (int mask = 16; mask < 64; mask <<= 1) {
      const float M2 = __shfl_xor(M, mask, 64);
      const float L2 = __shfl_xor(L, mask, 64);
      mlmerge(M, L, M2, L2);
    }
    if (g == 0) {
      part_m[(size_t)(sc*HEADS + h)*T + t0 + th*16 + l15] = M;
      part_l[(size_t)(sc*HEADS + h)*T + t0 + th*16 + l15] = L;
    }
  }
}

// ---------------- 11. merge partial (m,l) ----------------
__global__ __launch_bounds__(256) void ml_combine(
    const float* __restrict__ part_m, const float* __restrict__ part_l,
    float* __restrict__ m_fin, float* __restrict__ linv, int T)
{
  const int idx = blockIdx.x*256 + threadIdx.x;   // h*T + t
  const int t = idx & (T - 1);
  const int t0 = t & ~(TTL - 1);
  const int nsc = (t0 + TTL + SCHUNK - 1) / SCHUNK;
  float M = -1e30f, L = 0.f;
  for (int sc = 0; sc < nsc; sc++)
    mlmerge(M, L, part_m[(size_t)sc*HEADS*T + idx],
            part_l[(size_t)sc*HEADS*T + idx]);
  m_fin[idx] = M;
  linv[idx] = 1.f / L;
}

// ---------------- 12. attention phase B: apply, packed partial output --------
__global__ __launch_bounds__(1024) void attn_apply(
    const ushort_t* __restrict__ qbf, const ushort_t* __restrict__ kbf,
    const ushort_t* __restrict__ Vt, const float* __restrict__ hmb,
    const float* __restrict__ m_fin, const float* __restrict__ linv,
    float* __restrict__ P, int T)
{
  __shared__ ushort_t ybuf[HEADS*TTL*PADS];
  __shared__ float ep[TTL*EPS_STR];

  const int bid = blockIdx.x;
  const int sc = bid & 7;
  const int tb = (T/TTL) - 1 - (bid >> 3);
  const int t0 = tb * TTL;
  const int sbeg = sc * SCHUNK;
  if (sbeg >= t0 + TTL) return;
  const int send = (sbeg + SCHUNK < t0 + TTL) ? (sbeg + SCHUNK) : (t0 + TTL);
  // packed row base: sum_{j<sc}(T-256j) - 256*sc + t0 + row
  const int prow0 = T*sc - 128*sc*(sc-1) - SCHUNK*sc;

  const int tid = threadIdx.x;
  const int h = tid >> 6;
  const int lane = tid & 63;
  const int l15 = lane & 15, g = lane >> 4;
  const int tc = tid >> 5, scell = tid & 31;

  bf16x8 qf[2][2];
  float mt[2], li[2];
  #pragma unroll
  for (int th = 0; th < 2; th++) {
    #pragma unroll
    for (int kc = 0; kc < 2; kc++)
      qf[th][kc] = *(const bf16x8*)
          &qbf[(size_t)(t0 + th*16 + l15)*C_DIM + h*64 + kc*32 + g*8];
    mt[th] = m_fin[(size_t)h*T + t0 + th*16 + l15];
    li[th] = linv[(size_t)h*T + t0 + th*16 + l15];
  }
  const float slope = exp2f(-0.5f * (float)(h + 1));
  f32x4 oacc[2][4];
  #pragma unroll
  for (int th = 0; th < 2; th++)
    #pragma unroll
    for (int vf = 0; vf < 4; vf++) oacc[th][vf] = (f32x4){0.f,0.f,0.f,0.f};

  for (int s1 = sbeg; s1 < send; s1 += STL) {
    f32x4 acc[2][2];
    #pragma unroll
    for (int sh = 0; sh < 2; sh++)
      #pragma unroll
      for (int th = 0; th < 2; th++) acc[sh][th] = (f32x4){0.f,0.f,0.f,0.f};
    #pragma unroll
    for (int sh = 0; sh < 2; sh++)
      #pragma unroll
      for (int kc = 0; kc < 2; kc++) {
        const bf16x8 kf = *(const bf16x8*)
            &kbf[(size_t)(s1 + sh*16 + l15)*C_DIM + h*64 + kc*32 + g*8];
        #pragma unroll
        for (int th = 0; th < 2; th++)
          acc[sh][th] = MFMA16(kf, qf[th][kc], acc[sh][th]);
      }
    #pragma unroll
    for (int sh = 0; sh < 2; sh++)
      #pragma unroll
      for (int th = 0; th < 2; th++)
        pack4(&ybuf[(h*TTL + th*16 + l15)*PADS + sh*16 + g*4],
              acc[sh][th][0], acc[sh][th][1], acc[sh][th][2], acc[sh][th][3]);
    __syncthreads();
    {  // e_pre
      float hq[16], hk[16];
      #pragma unroll
      for (int q4 = 0; q4 < 4; q4++) {
        *(float4*)&hq[q4*4] = *(const float4*)&hmb[((size_t)0*T + t0+tc)*16 + q4*4];
        *(float4*)&hk[q4*4] = *(const float4*)&hmb[((size_t)1*T + s1+scell)*16 + q4*4];
      }
      float a = 0.f, b0 = 0.f, spk = 0.f;
      #pragma unroll
      for (int h2 = 0; h2 < 16; h2++) {
        const float y = bf2f(ybuf[(h2*TTL + tc)*PADS + scell]);
        a += y * hq[h2];
        b0 += y * hk[h2];
        spk += hk[h2];
      }
      ep[tc*EPS_STR + scell] = a*(1.f + spk) + b0;
    }
    __syncthreads();
    #pragma unroll
    for (int th = 0; th < 2; th++) {
      const int t = t0 + th*16 + l15;
      #pragma unroll
      for (int sh = 0; sh < 2; sh++)
        #pragma unroll
        for (int r = 0; r < 4; r++) {
          const int s = s1 + sh*16 + g*4 + r;
          float p = 0.f;
          if (s <= t) {
            const float y3 = acc[sh][th][r]
                + ep[(th*16 + l15)*EPS_STR + sh*16 + g*4 + r]
                - slope * (float)(t - s);
            p = __expf(y3 - mt[th]) * li[th];
          }
          acc[sh][th][r] = p;
        }
    }
    #pragma unroll
    for (int sh = 0; sh < 2; sh++)
      #pragma unroll
      for (int th = 0; th < 2; th++)
        pack4(&ybuf[(h*TTL + th*16 + l15)*PADS + sh*16 + g*4],
              acc[sh][th][0], acc[sh][th][1], acc[sh][th][2], acc[sh][th][3]);
    __syncthreads();
    {  // e_post
      float hq[16], hk[16];
      #pragma unroll
      for (int q4 = 0; q4 < 4; q4++) {
        *(float4*)&hq[q4*4] = *(const float4*)&hmb[((size_t)2*T + t0+tc)*16 + q4*4];
        *(float4*)&hk[q4*4] = *(const float4*)&hmb[((size_t)3*T + s1+scell)*16 + q4*4];
      }
      float cmx = 0.f, d0 = 0.f, spo = 0.f;
      #pragma unroll
      for (int h2 = 0; h2 < 16; h2++) {
        const float p = bf2f(ybuf[(h2*TTL + tc)*PADS + scell]);
        cmx += p * hq[h2];
        d0 += p * hk[h2];
        spo += hk[h2];
      }
      ep[tc*EPS_STR + scell] = cmx*(1.f + spo) + d0;
    }
    __syncthreads();
    #pragma unroll
    for (int sh = 0; sh < 2; sh++)
      #pragma unroll
      for (int th = 0; th < 2; th++) {
        const int ebase = (th*16 + l15)*EPS_STR + sh*16 + g*4;
        pack4(&ybuf[(h*TTL + th*16 + l15)*PADS + sh*16 + g*4],
              acc[sh][th][0] + ep[ebase+0], acc[sh][th][1] + ep[ebase+1],
              acc[sh][th][2] + ep[ebase+2], acc[sh][th][3] + ep[ebase+3]);
      }
    __syncthreads();
    #pragma unroll
    for (int th = 0; th < 2; th++) {
      const bf16x8 pa = *(const bf16x8*)&ybuf[(h*TTL + th*16 + l15)*PADS + g*8];
      #pragma unroll
      for (int vf = 0; vf < 4; vf++) {
        const bf16x8 vv = *(const bf16x8*)
            &Vt[(size_t)(h*64 + vf*16 + l15)*T + s1 + g*8];
        oacc[th][vf] = MFMA16(pa, vv, oacc[th][vf]);
      }
    }
    __syncthreads();
  }
  #pragma unroll
  for (int th = 0; th < 2; th++)
    #pragma unroll
    for (int vf = 0; vf < 4; vf++)
      #pragma unroll
      for (int r = 0; r < 4; r++)
        P[(size_t)(prow0 + t0 + th*16 + g*4 + r)*C_DIM
          + h*64 + vf*16 + l15] = oacc[th][vf][r];
}

// ---------------- 13. reduce partials + LayerNorm -> bf16 ----------------
__global__ __launch_bounds__(256) void reduce_ln(
    const float* __restrict__ P, ushort_t* __restrict__ outp,
    const float* __restrict__ g, const float* __restrict__ b, int T)
{
  __shared__ float red[4];
  const int t = blockIdx.x;
  const int tid = threadIdx.x;
  const int c = tid*4;
  const int nsc = (t >> 8) + 1;
  float4 v = make_float4(0.f, 0.f, 0.f, 0.f);
  int off = 0;
  for (int sc = 0; sc < nsc; sc++) {
    const int row = off + t - sc*SCHUNK;
    const float4 pv = *(const float4*)&P[(size_t)row*C_DIM + c];
    v.x += pv.x; v.y += pv.y; v.z += pv.z; v.w += pv.w;
    off += T - SCHUNK*sc;
  }
  float s = v.x+v.y+v.z+v.w;
  #pragma unroll
  for (int o = 32; o > 0; o >>= 1) s += __shfl_down(s, o, 64);
  if ((tid & 63) == 0) red[tid >> 6] = s;
  __syncthreads();
  const float mean = (red[0]+red[1]+red[2]+red[3]) * (1.0f/C_DIM);
  __syncthreads();
  const float d0 = v.x-mean, d1 = v.y-mean, d2 = v.z-mean, d3 = v.w-mean;
  float q = d0*d0 + d1*d1 + d2*d2 + d3*d3;
  #pragma unroll
  for (int o = 32; o > 0; o >>= 1) q += __shfl_down(q, o, 64);
  if ((tid & 63) == 0) red[tid >> 6] = q;
  __syncthreads();
  const float var = (red[0]+red[1]+red[2]+red[3]) * (1.0f/C_DIM);
  const float rstd = rsqrtf(var + 1e-5f);
  const float4 gv = *(const float4*)&g[c];
  const float4 bv = *(const float4*)&b[c];
  pack4(outp + (size_t)t*C_DIM + c,
        d0*rstd*gv.x + bv.x, d1*rstd*gv.y + bv.y,
        d2*rstd*gv.z + bv.z, d3*rstd*gv.w + bv.w);
}

// ---------------- launcher ----------------
extern "C" void kernel_launch(void* const* d_in, const int* in_sizes, int n_in,
                              void* d_out, int out_size, void* d_ws, size_t ws_size,
                              hipStream_t stream)
{
  const float* x      = (const float*)d_in[0];
  const float* shift  = (const float*)d_in[1];
  const float* maa_x  = (const float*)d_in[2];
  const float* maa_r  = (const float*)d_in[3];
  const float* maa_k  = (const float*)d_in[4];
  const float* maa_v  = (const float*)d_in[5];
  const float* w1     = (const float*)d_in[6];
  const float* w2     = (const float*)d_in[7];
  const float* hw1    = (const float*)d_in[8];
  const float* hw2    = (const float*)d_in[9];
  const float* w_r    = (const float*)d_in[10];
  const float* w_k    = (const float*)d_in[11];
  const float* w_v    = (const float*)d_in[12];
  const float* w_o    = (const float*)d_in[13];
  const float* ln_r_g = (const float*)d_in[14];
  const float* ln_r_b = (const float*)d_in[15];
  const float* ln_k_g = (const float*)d_in[16];
  const float* ln_k_b = (const float*)d_in[17];
  const float* ln_v_g = (const float*)d_in[18];
  const float* ln_v_b = (const float*)d_in[19];
  const float* ln_x_g = (const float*)d_in[20];
  const float* ln_x_b = (const float*)d_in[21];

  const int T = in_sizes[0] / C_DIM;            // 2048
  const size_t MM = (size_t)T * C_DIM;          // 2M f32 elems
  const size_t HF = MM / 2;                     // bf16 tensor in f32 units

  float* ws = (float*)d_ws;
  // --- alias region [0, 4.5*MM): packed partial P reuses attention-dead bufs
  float*    P      = ws;
  float*    dxprev = ws;                          // MM
  ushort_t* zbf    = (ushort_t*)(ws + MM);        // HF
  ushort_t* xbf    = (ushort_t*)(ws + MM + HF);   // HF
  float*    gtmp   = ws + 2*MM;                   // MM
  ushort_t* xqb    = (ushort_t*)(ws + 3*MM);      // HF
  ushort_t* xkb    = (ushort_t*)(ws + 3*MM + HF); // HF
  ushort_t* xvb    = (ushort_t*)(ws + 4*MM);      // HF
  // --- persistent region
  float* base2 = ws + 4*MM + HF;                  // = 4.5*MM
  ushort_t* qbf = (ushort_t*)(base2 + 0*HF);
  ushort_t* kbf = (ushort_t*)(base2 + 1*HF);
  ushort_t* vbf = (ushort_t*)(base2 + 2*HF);
  ushort_t* Vt  = (ushort_t*)(base2 + 3*HF);
  ushort_t* wtr = (ushort_t*)(base2 + 4*HF);      // 4 x C*C bf16 = 2*C*C f32u
  ushort_t* wtk = wtr + (size_t)C_DIM*C_DIM;
  ushort_t* wtv = wtk + (size_t)C_DIM*C_DIM;
  ushort_t* wto = wtv + (size_t)C_DIM*C_DIM;
  float* after_w = base2 + 4*HF + (size_t)2*C_DIM*C_DIM;   // FIXED: 2*C*C f32u
  ushort_t* wlt = (ushort_t*)after_w;             // 224*1024 bf16 = 114688 f32u
  float* xxx    = after_w + 131072;               // T*96
  float* ha     = xxx + (size_t)T*96;             // T*128
  float* hmb    = ha + (size_t)T*128;             // 4*T*16
  float* part_m = hmb + (size_t)4*T*16;           // 8*HEADS*T
  float* part_l = part_m + (size_t)8*HEADS*T;     // 8*HEADS*T
  float* m_fin  = part_l + (size_t)8*HEADS*T;     // HEADS*T
  float* linv   = m_fin + (size_t)HEADS*T;        // HEADS*T
  ushort_t* abf = (ushort_t*)(linv + (size_t)HEADS*T);  // HF

  prep_kernel<<<T, 256, 0, stream>>>(x, shift, maa_x, dxprev, zbf, xbf);
  wlora_prep<<<dim3(C_DIM/32, 7), 256, 0, stream>>>(w1, hw1, wlt);
  lora_gemm<<<dim3(T/32, 7), 64, 0, stream>>>(zbf, xbf, wlt, xxx, ha);
  mix_kernel<<<T/8, 256, 0, stream>>>(x, dxprev, xxx, maa_r, maa_k, maa_v, w2,
                                      xqb, xkb, xvb);
  hm_kernel<<<T/4, 256, 0, stream>>>(ha, hw2, hmb, T);
  wprep_kernel<<<dim3(32, 32, 4), 256, 0, stream>>>(
      w_r, w_k, w_v, w_o, wtr, wtk, wtv, wto);

  const int ggemm = (T/32) * (C_DIM/64);
  gemm_bf16<<<ggemm, 64, 0, stream>>>(xqb, wtr, gtmp);
  ln_rows<<<T, 256, 0, stream>>>(gtmp, qbf, ln_r_g, ln_r_b, 0.125f);
  gemm_bf16<<<ggemm, 64, 0, stream>>>(xkb, wtk, gtmp);
  ln_rows<<<T, 256, 0, stream>>>(gtmp, kbf, ln_k_g, ln_k_b, 1.0f);
  gemm_bf16<<<ggemm, 64, 0, stream>>>(xvb, wtv, gtmp);
  ln_rows<<<T, 256, 0, stream>>>(gtmp, vbf, ln_v_g, ln_v_b, 1.0f);
  vtrans_kernel<<<dim3(T/32, C_DIM/32), 256, 0, stream>>>(vbf, Vt, T);

  attn_stats<<<(T/TTL)*8, 1024, 0, stream>>>(qbf, kbf, hmb, part_m, part_l, T);
  ml_combine<<<(HEADS*T)/256, 256, 0, stream>>>(part_m, part_l, m_fin, linv, T);
  attn_apply<<<(T/TTL)*8, 1024, 0, stream>>>(
      qbf, kbf, Vt, hmb, m_fin, linv, P, T);

  reduce_ln<<<T, 256, 0, stream>>>(P, abf, ln_x_g, ln_x_b, T);
  gemm_bf16<<<ggemm, 64, 0, stream>>>(abf, wto, (float*)d_out);
}

// Round 5
// 525.671 us; speedup vs baseline: 4.0838x; 1.0884x over previous
//
#include <hip/hip_runtime.h>
#include <cstdint>
#include <cstddef>

// RWKV_Tmix_headmixer — round 5: latency-focused attention restructure.
// 16-row t-tiles, 512-thread blocks (8 waves x 2 heads), staged hm coeffs in
// LDS, 4 barriers/tile (apply) & 2 (stats), V prefetch, wave-local p2->PV.
// B=1, T=2048, C=1024, H=16, K=64.

#define C_DIM 1024
#define HEADS 16
#define TQ 16            // t rows per attention block
#define SCH 256          // s-chunk per block
#define PADS 40          // ybuf inner stride (bf16): 80 B rows, 16B-aligned
#define EPS 33           // ep f32 stride

typedef unsigned short ushort_t;
typedef __attribute__((ext_vector_type(8))) short bf16x8;
typedef __attribute__((ext_vector_type(4))) float f32x4;

#define MFMA16(a, b, c) __builtin_amdgcn_mfma_f32_16x16x32_bf16(a, b, c, 0, 0, 0)

__device__ __forceinline__ unsigned int f2bf_u(float f) {
  unsigned int u = __float_as_uint(f);
  return (u + 0x7fffu + ((u >> 16) & 1u)) >> 16;   // RNE
}
__device__ __forceinline__ float bf2f(ushort_t u) {
  return __uint_as_float(((unsigned int)u) << 16);
}
__device__ __forceinline__ void pack4(ushort_t* dst, float x0, float x1,
                                      float x2, float x3) {
  uint2 v;
  v.x = f2bf_u(x0) | (f2bf_u(x1) << 16);
  v.y = f2bf_u(x2) | (f2bf_u(x3) << 16);
  *(uint2*)dst = v;
}
__device__ __forceinline__ void mlmerge(float& M, float& L, float m2, float l2) {
  float nm = fmaxf(M, m2);
  float ea = (M  <= -1e29f) ? 0.f : __expf(M - nm);
  float eb = (m2 <= -1e29f) ? 0.f : __expf(m2 - nm);
  L = L * ea + l2 * eb;
  M = nm;
}

// ---------------- 1. prep: dxprev f32, z & x copies in bf16 ----------------
__global__ __launch_bounds__(256) void prep_kernel(
    const float* __restrict__ x, const float* __restrict__ shift,
    const float* __restrict__ maa_x,
    float* __restrict__ dxprev, ushort_t* __restrict__ zbf,
    ushort_t* __restrict__ xbf)
{
  const int t = blockIdx.x;
  const int c = threadIdx.x * 4;
  const size_t base = (size_t)t * C_DIM + c;
  const float4 xc = *(const float4*)&x[base];
  const float4 xp = (t == 0) ? *(const float4*)&shift[c]
                             : *(const float4*)&x[base - C_DIM];
  const float4 mx = *(const float4*)&maa_x[c];
  float4 d;
  d.x = xp.x - xc.x; d.y = xp.y - xc.y; d.z = xp.z - xc.z; d.w = xp.w - xc.w;
  *(float4*)&dxprev[base] = d;
  pack4(&zbf[base], xc.x + d.x*mx.x, xc.y + d.y*mx.y,
        xc.z + d.z*mx.z, xc.w + d.w*mx.w);
  pack4(&xbf[base], xc.x, xc.y, xc.z, xc.w);
}

// ---------------- 2. lora weight prep ----------------
__global__ __launch_bounds__(256) void wlora_prep(
    const float* __restrict__ w1, const float* __restrict__ hw1,
    ushort_t* __restrict__ wlt)
{
  __shared__ float tile[32][33];
  const int k0 = blockIdx.x*32, j0 = blockIdx.y*32;
  const int r = threadIdx.x >> 3, c4 = (threadIdx.x & 7) * 4;
  const float* W = (j0 < 96) ? w1 : hw1;
  const int stride = (j0 < 96) ? 96 : 128;
  const int jo = (j0 < 96) ? j0 : j0 - 96;
  const float4 v = *(const float4*)&W[(size_t)(k0+r)*stride + jo + c4];
  tile[r][c4+0] = v.x; tile[r][c4+1] = v.y;
  tile[r][c4+2] = v.z; tile[r][c4+3] = v.w;
  __syncthreads();
  pack4(&wlt[(size_t)(j0+r)*C_DIM + k0 + c4],
        tile[c4+0][r], tile[c4+1][r], tile[c4+2][r], tile[c4+3][r]);
}

// ---------------- 3. lora GEMM with tanh epilogue ----------------
__global__ __launch_bounds__(64) void lora_gemm(
    const ushort_t* __restrict__ zbf, const ushort_t* __restrict__ xbf,
    const ushort_t* __restrict__ wlt, float* __restrict__ xxx,
    float* __restrict__ ha)
{
  const int nt = blockIdx.y;
  const int bm = blockIdx.x * 32;
  const ushort_t* A = (nt < 3) ? zbf : xbf;
  const int wrow = nt * 32;
  const int lane = threadIdx.x;
  const int l15 = lane & 15, g = lane >> 4;
  f32x4 acc[2][2];
  #pragma unroll
  for (int i = 0; i < 2; i++)
    #pragma unroll
    for (int j = 0; j < 2; j++) acc[i][j] = (f32x4){0.f,0.f,0.f,0.f};
  bf16x8 a0[2], b0[2], a1[2], b1[2];
  #define LLA(dst, kk) { \
    dst[0] = *(const bf16x8*)&A[(size_t)(bm + l15)*C_DIM + (kk) + g*8]; \
    dst[1] = *(const bf16x8*)&A[(size_t)(bm + 16 + l15)*C_DIM + (kk) + g*8]; }
  #define LLB(dst, kk) { \
    dst[0] = *(const bf16x8*)&wlt[(size_t)(wrow + l15)*C_DIM + (kk) + g*8]; \
    dst[1] = *(const bf16x8*)&wlt[(size_t)(wrow + 16 + l15)*C_DIM + (kk) + g*8]; }
  LLA(a0, 0); LLB(b0, 0);
  for (int k0 = 0; k0 < C_DIM; k0 += 64) {
    LLA(a1, k0+32); LLB(b1, k0+32);
    #pragma unroll
    for (int i = 0; i < 2; i++)
      #pragma unroll
      for (int j = 0; j < 2; j++) acc[i][j] = MFMA16(a0[i], b0[j], acc[i][j]);
    if (k0 + 64 < C_DIM) { LLA(a0, k0+64); LLB(b0, k0+64); }
    #pragma unroll
    for (int i = 0; i < 2; i++)
      #pragma unroll
      for (int j = 0; j < 2; j++) acc[i][j] = MFMA16(a1[i], b1[j], acc[i][j]);
  }
  #undef LLA
  #undef LLB
  #pragma unroll
  for (int i = 0; i < 2; i++)
    #pragma unroll
    for (int j = 0; j < 2; j++)
      #pragma unroll
      for (int r = 0; r < 4; r++) {
        const int t = bm + i*16 + g*4 + r;
        const int col = wrow + j*16 + l15;
        const float val = tanhf(acc[i][j][r]);
        if (nt < 3) xxx[(size_t)t*96 + col] = val;
        else        ha[(size_t)t*128 + col - 96] = val;
      }
}

// ---------------- 4. mix: xq/xk/xv (bf16), 8 rows/block ----------------
__global__ __launch_bounds__(256) void mix_kernel(
    const float* __restrict__ x, const float* __restrict__ dxp,
    const float* __restrict__ xxx,
    const float* __restrict__ maa_r, const float* __restrict__ maa_k,
    const float* __restrict__ maa_v, const float* __restrict__ w2,
    ushort_t* __restrict__ xq, ushort_t* __restrict__ xk,
    ushort_t* __restrict__ xv)
{
  __shared__ float xs[8][96];
  const int t0 = blockIdx.x * 8;
  const int tid = threadIdx.x;
  #pragma unroll
  for (int i = 0; i < 3; i++) {
    const int u = tid + i*256;
    if (u < 768) {
      const int r = u / 96, cc = u % 96;
      xs[r][cc] = xxx[(size_t)(t0+r)*96 + cc];
    }
  }
  __syncthreads();
  const int c = tid * 4;
  float4 xc[8], dx[8];
  #pragma unroll
  for (int r = 0; r < 8; r++) {
    xc[r] = *(const float4*)&x[(size_t)(t0+r)*C_DIM + c];
    dx[r] = *(const float4*)&dxp[(size_t)(t0+r)*C_DIM + c];
  }
  const float* maas[3] = {maa_r, maa_k, maa_v};
  ushort_t* outs[3] = {xq, xk, xv};
  #pragma unroll
  for (int n = 0; n < 3; n++) {
    const float4 mv = *(const float4*)&maas[n][c];
    float m[8][4];
    #pragma unroll
    for (int r = 0; r < 8; r++) {
      m[r][0] = mv.x; m[r][1] = mv.y; m[r][2] = mv.z; m[r][3] = mv.w;
    }
    #pragma unroll 8
    for (int d = 0; d < 32; d++) {
      const float4 w = *(const float4*)&w2[((size_t)n*32 + d)*C_DIM + c];
      #pragma unroll
      for (int r = 0; r < 8; r++) {
        const float xv2 = xs[r][n*32 + d];
        m[r][0] += xv2*w.x; m[r][1] += xv2*w.y;
        m[r][2] += xv2*w.z; m[r][3] += xv2*w.w;
      }
    }
    #pragma unroll
    for (int r = 0; r < 8; r++)
      pack4(&outs[n][(size_t)(t0+r)*C_DIM + c],
            xc[r].x + dx[r].x*m[r][0], xc[r].y + dx[r].y*m[r][1],
            xc[r].z + dx[r].z*m[r][2], xc[r].w + dx[r].w*m[r][3]);
  }
}

// ---------------- 5. hm ----------------
__global__ __launch_bounds__(256) void hm_kernel(
    const float* __restrict__ ha, const float* __restrict__ hw2,
    float* __restrict__ hm, int T)
{
  const int t = blockIdx.x*4 + (threadIdx.x >> 6);
  const int u = threadIdx.x & 63;
  const int n = u >> 4, h = u & 15;
  float s = 0.f;
  #pragma unroll 8
  for (int d = 0; d < 32; d++)
    s += ha[(size_t)t*128 + n*32 + d] * hw2[(size_t)(n*32 + d)*16 + h];
  hm[((size_t)n*T + t)*16 + h] = s * (1.f/16.f);
}

// ---------------- 6. weight prep: W[k][n] f32 -> Wt[n][k] bf16 ----------------
__global__ __launch_bounds__(256) void wprep_kernel(
    const float* __restrict__ w0, const float* __restrict__ w1,
    const float* __restrict__ w2, const float* __restrict__ w3,
    ushort_t* __restrict__ o0, ushort_t* __restrict__ o1,
    ushort_t* __restrict__ o2, ushort_t* __restrict__ o3)
{
  const float* W; ushort_t* O;
  if (blockIdx.z == 0)      { W = w0; O = o0; }
  else if (blockIdx.z == 1) { W = w1; O = o1; }
  else if (blockIdx.z == 2) { W = w2; O = o2; }
  else                      { W = w3; O = o3; }
  __shared__ float tile[32][33];
  const int k0 = blockIdx.x*32, n0 = blockIdx.y*32;
  const int r = threadIdx.x >> 3, c4 = (threadIdx.x & 7) * 4;
  const float4 v = *(const float4*)&W[(size_t)(k0+r)*C_DIM + n0 + c4];
  tile[r][c4+0] = v.x; tile[r][c4+1] = v.y;
  tile[r][c4+2] = v.z; tile[r][c4+3] = v.w;
  __syncthreads();
  pack4(&O[(size_t)(n0+r)*C_DIM + k0 + c4],
        tile[c4+0][r], tile[c4+1][r], tile[c4+2][r], tile[c4+3][r]);
}

// ---------------- 7. bf16 MFMA GEMM ----------------
__global__ __launch_bounds__(64) void gemm_bf16(
    const ushort_t* __restrict__ A, const ushort_t* __restrict__ Bt,
    float* __restrict__ Cm)
{
  const int bid = blockIdx.x;
  const int bn = (bid & 15) * 64;
  const int bm = (bid >> 4) * 32;
  const int lane = threadIdx.x;
  const int l15 = lane & 15, g = lane >> 4;
  f32x4 acc[2][4];
  #pragma unroll
  for (int i = 0; i < 2; i++)
    #pragma unroll
    for (int j = 0; j < 4; j++) acc[i][j] = (f32x4){0.f,0.f,0.f,0.f};
  bf16x8 a0[2], b0[4], a1[2], b1[4];
  #define LGA(dst, kk) { \
    _Pragma("unroll") \
    for (int i = 0; i < 2; i++) \
      dst[i] = *(const bf16x8*)&A[(size_t)(bm + i*16 + l15)*C_DIM + (kk) + g*8]; }
  #define LGB(dst, kk) { \
    _Pragma("unroll") \
    for (int j = 0; j < 4; j++) \
      dst[j] = *(const bf16x8*)&Bt[(size_t)(bn + j*16 + l15)*C_DIM + (kk) + g*8]; }
  LGA(a0, 0); LGB(b0, 0);
  for (int k0 = 0; k0 < C_DIM; k0 += 64) {
    LGA(a1, k0+32); LGB(b1, k0+32);
    #pragma unroll
    for (int i = 0; i < 2; i++)
      #pragma unroll
      for (int j = 0; j < 4; j++) acc[i][j] = MFMA16(a0[i], b0[j], acc[i][j]);
    if (k0 + 64 < C_DIM) { LGA(a0, k0+64); LGB(b0, k0+64); }
    #pragma unroll
    for (int i = 0; i < 2; i++)
      #pragma unroll
      for (int j = 0; j < 4; j++) acc[i][j] = MFMA16(a1[i], b1[j], acc[i][j]);
  }
  #undef LGA
  #undef LGB
  #pragma unroll
  for (int i = 0; i < 2; i++)
    #pragma unroll
    for (int j = 0; j < 4; j++)
      #pragma unroll
      for (int r = 0; r < 4; r++)
        Cm[(size_t)(bm + i*16 + g*4 + r)*C_DIM + bn + j*16 + l15] = acc[i][j][r];
}

// ---------------- 8. row LayerNorm -> bf16 ----------------
__global__ __launch_bounds__(256) void ln_rows(
    const float* __restrict__ in, ushort_t* __restrict__ outp,
    const float* __restrict__ g, const float* __restrict__ b, float scale)
{
  __shared__ float red[4];
  const int t = blockIdx.x;
  const int tid = threadIdx.x;
  const int c = tid*4;
  const float4 v = *(const float4*)&in[(size_t)t*C_DIM + c];
  float s = v.x+v.y+v.z+v.w;
  #pragma unroll
  for (int off = 32; off > 0; off >>= 1) s += __shfl_down(s, off, 64);
  if ((tid & 63) == 0) red[tid >> 6] = s;
  __syncthreads();
  const float mean = (red[0]+red[1]+red[2]+red[3]) * (1.0f/C_DIM);
  __syncthreads();
  const float d0 = v.x-mean, d1 = v.y-mean, d2 = v.z-mean, d3 = v.w-mean;
  float q = d0*d0 + d1*d1 + d2*d2 + d3*d3;
  #pragma unroll
  for (int off = 32; off > 0; off >>= 1) q += __shfl_down(q, off, 64);
  if ((tid & 63) == 0) red[tid >> 6] = q;
  __syncthreads();
  const float var = (red[0]+red[1]+red[2]+red[3]) * (1.0f/C_DIM);
  const float rstd = rsqrtf(var + 1e-5f);
  const float4 gv = *(const float4*)&g[c];
  const float4 bv = *(const float4*)&b[c];
  pack4(outp + (size_t)t*C_DIM + c,
        (d0*rstd*gv.x + bv.x)*scale, (d1*rstd*gv.y + bv.y)*scale,
        (d2*rstd*gv.z + bv.z)*scale, (d3*rstd*gv.w + bv.w)*scale);
}

// ---------------- 9. V transpose ----------------
__global__ __launch_bounds__(256) void vtrans_kernel(
    const ushort_t* __restrict__ vbf, ushort_t* __restrict__ Vt, int T)
{
  __shared__ ushort_t tile[32][36];
  const int t0 = blockIdx.x*32, c0 = blockIdx.y*32;
  const int r = threadIdx.x >> 3, c4 = (threadIdx.x & 7) * 4;
  const uint2 raw = *(const uint2*)&vbf[(size_t)(t0+r)*C_DIM + c0 + c4];
  tile[r][c4+0] = (ushort_t)(raw.x & 0xffffu);
  tile[r][c4+1] = (ushort_t)(raw.x >> 16);
  tile[r][c4+2] = (ushort_t)(raw.y & 0xffffu);
  tile[r][c4+3] = (ushort_t)(raw.y >> 16);
  __syncthreads();
  uint2 w;
  w.x = (unsigned)tile[c4+0][r] | ((unsigned)tile[c4+1][r] << 16);
  w.y = (unsigned)tile[c4+2][r] | ((unsigned)tile[c4+3][r] << 16);
  *(uint2*)&Vt[(size_t)(c0+r)*T + t0 + c4] = w;
}

// ---------------- 10. attention phase A: softmax stats ----------------
// grid (8, T/16); 512 thr = 8 waves x 2 heads; 2 barriers/tile.
__global__ __launch_bounds__(512, 4) void attn_stats(
    const ushort_t* __restrict__ qbf, const ushort_t* __restrict__ kbf,
    const float* __restrict__ hmb, float* __restrict__ part_m,
    float* __restrict__ part_l, int T)
{
  __shared__ ushort_t ybuf[HEADS*TQ*PADS];
  __shared__ float ep[TQ*EPS];
  __shared__ float hpqf[TQ*16];
  __shared__ float hpkf[SCH*16];
  __shared__ float spk_l[SCH];

  const int sc = blockIdx.x;
  const int tb = (int)gridDim.y - 1 - (int)blockIdx.y;   // longest-first
  const int t0 = tb * TQ;
  const int sbeg = sc * SCH;
  if (sbeg >= t0 + TQ) return;
  const int send = (sbeg + SCH < t0 + TQ) ? (sbeg + SCH) : (t0 + TQ);

  const int tid = threadIdx.x;
  const int w = tid >> 6, lane = tid & 63, l15 = lane & 15, g = lane >> 4;
  const int tc = tid >> 5, scell = tid & 31;

  for (int i = tid; i < SCH*16; i += 512)
    hpkf[i] = hmb[((size_t)1*T + sbeg)*16 + i];
  if (tid < TQ*16)
    hpqf[tid] = hmb[((size_t)0*T + t0)*16 + tid];
  if (tid < SCH) {
    const float* src = hmb + ((size_t)1*T + sbeg + tid)*16;
    float s = 0.f;
    #pragma unroll
    for (int q4 = 0; q4 < 4; q4++) {
      const float4 v = *(const float4*)&src[q4*4];
      s += v.x + v.y + v.z + v.w;
    }
    spk_l[tid] = s;
  }

  const int hh[2] = {w, w + 8};
  bf16x8 qf[2][2];
  float slope[2];
  #pragma unroll
  for (int hd = 0; hd < 2; hd++) {
    #pragma unroll
    for (int kc = 0; kc < 2; kc++)
      qf[hd][kc] = *(const bf16x8*)
          &qbf[(size_t)(t0 + l15)*C_DIM + hh[hd]*64 + kc*32 + g*8];
    slope[hd] = exp2f(-0.5f * (float)(hh[hd] + 1));
  }
  float mrun[2] = {-1e30f, -1e30f}, lrun[2] = {0.f, 0.f};

  for (int s1 = sbeg; s1 < send; s1 += 32) {
    f32x4 acc[2][2];
    #pragma unroll
    for (int hd = 0; hd < 2; hd++)
      #pragma unroll
      for (int sh = 0; sh < 2; sh++) acc[hd][sh] = (f32x4){0.f,0.f,0.f,0.f};
    #pragma unroll
    for (int hd = 0; hd < 2; hd++) {
      #pragma unroll
      for (int sh = 0; sh < 2; sh++)
        #pragma unroll
        for (int kc = 0; kc < 2; kc++) {
          const bf16x8 kf = *(const bf16x8*)
              &kbf[(size_t)(s1 + sh*16 + l15)*C_DIM + hh[hd]*64 + kc*32 + g*8];
          acc[hd][sh] = MFMA16(kf, qf[hd][kc], acc[hd][sh]);
        }
      #pragma unroll
      for (int sh = 0; sh < 2; sh++)
        pack4(&ybuf[(size_t)(hh[hd]*TQ + l15)*PADS + sh*16 + g*4],
              acc[hd][sh][0], acc[hd][sh][1], acc[hd][sh][2], acc[hd][sh][3]);
    }
    __syncthreads();                     // y0 ready
    {
      const int so = s1 - sbeg + scell;
      float a = 0.f, b0 = 0.f;
      #pragma unroll
      for (int h2 = 0; h2 < 16; h2++) {
        const float y = bf2f(ybuf[(h2*TQ + tc)*PADS + scell]);
        a  += y * hpqf[tc*16 + h2];
        b0 += y * hpkf[so*16 + h2];
      }
      ep[tc*EPS + scell] = a*(1.f + spk_l[so]) + b0;
    }
    __syncthreads();                     // ep ready; ybuf free
    #pragma unroll
    for (int hd = 0; hd < 2; hd++) {
      const int t = t0 + l15;
      #pragma unroll
      for (int sh = 0; sh < 2; sh++)
        #pragma unroll
        for (int r = 0; r < 4; r++) {
          const int s = s1 + sh*16 + g*4 + r;
          if (s <= t) {
            const float y3 = acc[hd][sh][r] + ep[l15*EPS + sh*16 + g*4 + r]
                - slope[hd]*(float)(t - s);
            const float d = y3 - mrun[hd];
            if (d > 0.f) { lrun[hd] = lrun[hd]*__expf(-d) + 1.f; mrun[hd] = y3; }
            else lrun[hd] += __expf(d);
          }
        }
    }
  }
  #pragma unroll
  for (int hd = 0; hd < 2; hd++) {
    float M = mrun[hd], L = lrun[hd];
    #pragma unroll
    for (int mask = 16; mask < 64; mask <<= 1) {
      const float M2 = __shfl_xor(M, mask, 64);
      const float L2 = __shfl_xor(L, mask, 64);
      mlmerge(M, L, M2, L2);
    }
    if (g == 0) {
      part_m[(size_t)(sc*HEADS + hh[hd])*T + t0 + l15] = M;
      part_l[(size_t)(sc*HEADS + hh[hd])*T + t0 + l15] = L;
    }
  }
}

// ---------------- 11. merge partial (m,l) ----------------
__global__ __launch_bounds__(256) void ml_combine(
    const float* __restrict__ part_m, const float* __restrict__ part_l,
    float* __restrict__ m_fin, float* __restrict__ linv, int T)
{
  const int idx = blockIdx.x*256 + threadIdx.x;   // h*T + t
  const int t = idx & (T - 1);
  const int nsc = (t >> 8) + 1;
  float M = -1e30f, L = 0.f;
  for (int sc = 0; sc < nsc; sc++)
    mlmerge(M, L, part_m[(size_t)sc*HEADS*T + idx],
            part_l[(size_t)sc*HEADS*T + idx]);
  m_fin[idx] = M;
  linv[idx] = 1.f / L;
}

// ---------------- 12. attention phase B: apply ----------------
// grid (8, T/16); 512 thr; 4 barriers/tile; packed f32 partial P.
__global__ __launch_bounds__(512, 4) void attn_apply(
    const ushort_t* __restrict__ qbf, const ushort_t* __restrict__ kbf,
    const ushort_t* __restrict__ Vt, const float* __restrict__ hmb,
    const float* __restrict__ m_fin, const float* __restrict__ linv,
    float* __restrict__ P, int T)
{
  __shared__ ushort_t ybuf[HEADS*TQ*PADS];
  __shared__ float ep[TQ*EPS];
  __shared__ float hpqf[TQ*16], hoqf[TQ*16];
  __shared__ float hpkf[SCH*16], hokf[SCH*16];
  __shared__ float spk_l[SCH], spo_l[SCH];

  const int sc = blockIdx.x;
  const int tb = (int)gridDim.y - 1 - (int)blockIdx.y;
  const int t0 = tb * TQ;
  const int sbeg = sc * SCH;
  if (sbeg >= t0 + TQ) return;
  const int send = (sbeg + SCH < t0 + TQ) ? (sbeg + SCH) : (t0 + TQ);
  const int prow0 = T*sc - 128*sc*(sc-1) - SCH*sc;   // packed chunk base - SCH*sc

  const int tid = threadIdx.x;
  const int w = tid >> 6, lane = tid & 63, l15 = lane & 15, g = lane >> 4;
  const int tc = tid >> 5, scell = tid & 31;

  for (int i = tid; i < SCH*16; i += 512) {
    hpkf[i] = hmb[((size_t)1*T + sbeg)*16 + i];
    hokf[i] = hmb[((size_t)3*T + sbeg)*16 + i];
  }
  if (tid < TQ*16) {
    hpqf[tid] = hmb[((size_t)0*T + t0)*16 + tid];
    hoqf[tid] = hmb[((size_t)2*T + t0)*16 + tid];
  }
  {
    const int s_l = tid & 255;
    const float* src = hmb + ((size_t)((tid < 256) ? 1 : 3)*T + sbeg + s_l)*16;
    float s = 0.f;
    #pragma unroll
    for (int q4 = 0; q4 < 4; q4++) {
      const float4 v = *(const float4*)&src[q4*4];
      s += v.x + v.y + v.z + v.w;
    }
    if (tid < 256) spk_l[s_l] = s; else spo_l[s_l] = s;
  }

  const int hh[2] = {w, w + 8};
  bf16x8 qf[2][2];
  float mt[2], li[2], slope[2];
  #pragma unroll
  for (int hd = 0; hd < 2; hd++) {
    #pragma unroll
    for (int kc = 0; kc < 2; kc++)
      qf[hd][kc] = *(const bf16x8*)
          &qbf[(size_t)(t0 + l15)*C_DIM + hh[hd]*64 + kc*32 + g*8];
    mt[hd] = m_fin[(size_t)hh[hd]*T + t0 + l15];
    li[hd] = linv[(size_t)hh[hd]*T + t0 + l15];
    slope[hd] = exp2f(-0.5f * (float)(hh[hd] + 1));
  }
  f32x4 oacc[2][4];
  #pragma unroll
  for (int hd = 0; hd < 2; hd++)
    #pragma unroll
    for (int vf = 0; vf < 4; vf++) oacc[hd][vf] = (f32x4){0.f,0.f,0.f,0.f};

  for (int s1 = sbeg; s1 < send; s1 += 32) {
    f32x4 acc[2][2];
    #pragma unroll
    for (int hd = 0; hd < 2; hd++)
      #pragma unroll
      for (int sh = 0; sh < 2; sh++) acc[hd][sh] = (f32x4){0.f,0.f,0.f,0.f};
    #pragma unroll
    for (int hd = 0; hd < 2; hd++) {
      #pragma unroll
      for (int sh = 0; sh < 2; sh++)
        #pragma unroll
        for (int kc = 0; kc < 2; kc++) {
          const bf16x8 kf = *(const bf16x8*)
              &kbf[(size_t)(s1 + sh*16 + l15)*C_DIM + hh[hd]*64 + kc*32 + g*8];
          acc[hd][sh] = MFMA16(kf, qf[hd][kc], acc[hd][sh]);
        }
      #pragma unroll
      for (int sh = 0; sh < 2; sh++)
        pack4(&ybuf[(size_t)(hh[hd]*TQ + l15)*PADS + sh*16 + g*4],
              acc[hd][sh][0], acc[hd][sh][1], acc[hd][sh][2], acc[hd][sh][3]);
    }
    __syncthreads();                     // bar1: y0 ready
    {
      const int so = s1 - sbeg + scell;
      float a = 0.f, b0 = 0.f;
      #pragma unroll
      for (int h2 = 0; h2 < 16; h2++) {
        const float y = bf2f(ybuf[(h2*TQ + tc)*PADS + scell]);
        a  += y * hpqf[tc*16 + h2];
        b0 += y * hpkf[so*16 + h2];
      }
      ep[tc*EPS + scell] = a*(1.f + spk_l[so]) + b0;
    }
    __syncthreads();                     // bar2: ep ready; ybuf free
    #pragma unroll
    for (int hd = 0; hd < 2; hd++) {
      const int t = t0 + l15;
      #pragma unroll
      for (int sh = 0; sh < 2; sh++) {
        #pragma unroll
        for (int r = 0; r < 4; r++) {
          const int s = s1 + sh*16 + g*4 + r;
          float p = 0.f;
          if (s <= t) {
            const float y3 = acc[hd][sh][r] + ep[l15*EPS + sh*16 + g*4 + r]
                - slope[hd]*(float)(t - s);
            p = __expf(y3 - mt[hd]) * li[hd];
          }
          acc[hd][sh][r] = p;
        }
        pack4(&ybuf[(size_t)(hh[hd]*TQ + l15)*PADS + sh*16 + g*4],
              acc[hd][sh][0], acc[hd][sh][1], acc[hd][sh][2], acc[hd][sh][3]);
      }
    }
    // prefetch V fragments (independent of LDS phases)
    bf16x8 vv[2][4];
    #pragma unroll
    for (int hd = 0; hd < 2; hd++)
      #pragma unroll
      for (int vf = 0; vf < 4; vf++)
        vv[hd][vf] = *(const bf16x8*)
            &Vt[(size_t)(hh[hd]*64 + vf*16 + l15)*T + s1 + g*8];
    __syncthreads();                     // bar3: p ready
    {
      const int so = s1 - sbeg + scell;
      float cm = 0.f, d0 = 0.f;
      #pragma unroll
      for (int h2 = 0; h2 < 16; h2++) {
        const float pv = bf2f(ybuf[(h2*TQ + tc)*PADS + scell]);
        cm += pv * hoqf[tc*16 + h2];
        d0 += pv * hokf[so*16 + h2];
      }
      ep[tc*EPS + scell] = cm*(1.f + spo_l[so]) + d0;
    }
    __syncthreads();                     // bar4: ep2 ready; ybuf(p) free
    #pragma unroll
    for (int hd = 0; hd < 2; hd++) {
      #pragma unroll
      for (int sh = 0; sh < 2; sh++) {
        const int eb = l15*EPS + sh*16 + g*4;
        pack4(&ybuf[(size_t)(hh[hd]*TQ + l15)*PADS + sh*16 + g*4],
              acc[hd][sh][0] + ep[eb+0], acc[hd][sh][1] + ep[eb+1],
              acc[hd][sh][2] + ep[eb+2], acc[hd][sh][3] + ep[eb+3]);
      }
      // wave-local: this wave wrote these rows; DS ops complete in order
      const bf16x8 pa = *(const bf16x8*)
          &ybuf[(size_t)(hh[hd]*TQ + l15)*PADS + g*8];
      #pragma unroll
      for (int vf = 0; vf < 4; vf++)
        oacc[hd][vf] = MFMA16(pa, vv[hd][vf], oacc[hd][vf]);
    }
    // no end barrier: next y0 pack touches only own-wave rows; cross-head
    // readers (e_post) completed before bar4.
  }
  #pragma unroll
  for (int hd = 0; hd < 2; hd++)
    #pragma unroll
    for (int vf = 0; vf < 4; vf++)
      #pragma unroll
      for (int r = 0; r < 4; r++)
        P[(size_t)(prow0 + t0 + g*4 + r)*C_DIM + hh[hd]*64 + vf*16 + l15]
            = oacc[hd][vf][r];
}

// ---------------- 13. reduce partials + LayerNorm -> bf16 ----------------
__global__ __launch_bounds__(256) void reduce_ln(
    const float* __restrict__ P, ushort_t* __restrict__ outp,
    const float* __restrict__ g, const float* __restrict__ b, int T)
{
  __shared__ float red[4];
  const int t = blockIdx.x;
  const int tid = threadIdx.x;
  const int c = tid*4;
  const int nsc = (t >> 8) + 1;
  float4 v = make_float4(0.f, 0.f, 0.f, 0.f);
  int off = 0;
  for (int sc = 0; sc < nsc; sc++) {
    const int row = off + t - sc*SCH;
    const float4 pv = *(const float4*)&P[(size_t)row*C_DIM + c];
    v.x += pv.x; v.y += pv.y; v.z += pv.z; v.w += pv.w;
    off += T - SCH*sc;
  }
  float s = v.x+v.y+v.z+v.w;
  #pragma unroll
  for (int o = 32; o > 0; o >>= 1) s += __shfl_down(s, o, 64);
  if ((tid & 63) == 0) red[tid >> 6] = s;
  __syncthreads();
  const float mean = (red[0]+red[1]+red[2]+red[3]) * (1.0f/C_DIM);
  __syncthreads();
  const float d0 = v.x-mean, d1 = v.y-mean, d2 = v.z-mean, d3 = v.w-mean;
  float q = d0*d0 + d1*d1 + d2*d2 + d3*d3;
  #pragma unroll
  for (int o = 32; o > 0; o >>= 1) q += __shfl_down(q, o, 64);
  if ((tid & 63) == 0) red[tid >> 6] = q;
  __syncthreads();
  const float var = (red[0]+red[1]+red[2]+red[3]) * (1.0f/C_DIM);
  const float rstd = rsqrtf(var + 1e-5f);
  const float4 gv = *(const float4*)&g[c];
  const float4 bv = *(const float4*)&b[c];
  pack4(outp + (size_t)t*C_DIM + c,
        d0*rstd*gv.x + bv.x, d1*rstd*gv.y + bv.y,
        d2*rstd*gv.z + bv.z, d3*rstd*gv.w + bv.w);
}

// ---------------- launcher ----------------
extern "C" void kernel_launch(void* const* d_in, const int* in_sizes, int n_in,
                              void* d_out, int out_size, void* d_ws, size_t ws_size,
                              hipStream_t stream)
{
  const float* x      = (const float*)d_in[0];
  const float* shift  = (const float*)d_in[1];
  const float* maa_x  = (const float*)d_in[2];
  const float* maa_r  = (const float*)d_in[3];
  const float* maa_k  = (const float*)d_in[4];
  const float* maa_v  = (const float*)d_in[5];
  const float* w1     = (const float*)d_in[6];
  const float* w2     = (const float*)d_in[7];
  const float* hw1    = (const float*)d_in[8];
  const float* hw2    = (const float*)d_in[9];
  const float* w_r    = (const float*)d_in[10];
  const float* w_k    = (const float*)d_in[11];
  const float* w_v    = (const float*)d_in[12];
  const float* w_o    = (const float*)d_in[13];
  const float* ln_r_g = (const float*)d_in[14];
  const float* ln_r_b = (const float*)d_in[15];
  const float* ln_k_g = (const float*)d_in[16];
  const float* ln_k_b = (const float*)d_in[17];
  const float* ln_v_g = (const float*)d_in[18];
  const float* ln_v_b = (const float*)d_in[19];
  const float* ln_x_g = (const float*)d_in[20];
  const float* ln_x_b = (const float*)d_in[21];

  const int T = in_sizes[0] / C_DIM;            // 2048
  const size_t MM = (size_t)T * C_DIM;          // 2M f32 elems
  const size_t HF = MM / 2;                     // bf16 tensor in f32 units

  float* ws = (float*)d_ws;
  // --- alias region [0, 4.5*MM): packed partial P reuses attention-dead bufs
  float*    P      = ws;
  float*    dxprev = ws;                          // MM
  ushort_t* zbf    = (ushort_t*)(ws + MM);        // HF
  ushort_t* xbf    = (ushort_t*)(ws + MM + HF);   // HF
  float*    gtmp   = ws + 2*MM;                   // MM
  ushort_t* xqb    = (ushort_t*)(ws + 3*MM);      // HF
  ushort_t* xkb    = (ushort_t*)(ws + 3*MM + HF); // HF
  ushort_t* xvb    = (ushort_t*)(ws + 4*MM);      // HF
  // --- persistent region
  float* base2 = ws + 4*MM + HF;                  // = 4.5*MM
  ushort_t* qbf = (ushort_t*)(base2 + 0*HF);
  ushort_t* kbf = (ushort_t*)(base2 + 1*HF);
  ushort_t* vbf = (ushort_t*)(base2 + 2*HF);
  ushort_t* Vt  = (ushort_t*)(base2 + 3*HF);
  ushort_t* wtr = (ushort_t*)(base2 + 4*HF);      // 4 x C*C bf16 = 2*C*C f32u
  ushort_t* wtk = wtr + (size_t)C_DIM*C_DIM;
  ushort_t* wtv = wtk + (size_t)C_DIM*C_DIM;
  ushort_t* wto = wtv + (size_t)C_DIM*C_DIM;
  float* after_w = base2 + 4*HF + (size_t)2*C_DIM*C_DIM;
  ushort_t* wlt = (ushort_t*)after_w;             // 224*1024 bf16
  float* xxx    = after_w + 131072;               // T*96
  float* ha     = xxx + (size_t)T*96;             // T*128
  float* hmb    = ha + (size_t)T*128;             // 4*T*16
  float* part_m = hmb + (size_t)4*T*16;           // 8*HEADS*T
  float* part_l = part_m + (size_t)8*HEADS*T;     // 8*HEADS*T
  float* m_fin  = part_l + (size_t)8*HEADS*T;     // HEADS*T
  float* linv   = m_fin + (size_t)HEADS*T;        // HEADS*T
  ushort_t* abf = (ushort_t*)(linv + (size_t)HEADS*T);  // HF

  prep_kernel<<<T, 256, 0, stream>>>(x, shift, maa_x, dxprev, zbf, xbf);
  wlora_prep<<<dim3(C_DIM/32, 7), 256, 0, stream>>>(w1, hw1, wlt);
  lora_gemm<<<dim3(T/32, 7), 64, 0, stream>>>(zbf, xbf, wlt, xxx, ha);
  mix_kernel<<<T/8, 256, 0, stream>>>(x, dxprev, xxx, maa_r, maa_k, maa_v, w2,
                                      xqb, xkb, xvb);
  hm_kernel<<<T/4, 256, 0, stream>>>(ha, hw2, hmb, T);
  wprep_kernel<<<dim3(32, 32, 4), 256, 0, stream>>>(
      w_r, w_k, w_v, w_o, wtr, wtk, wtv, wto);

  const int ggemm = (T/32) * (C_DIM/64);
  gemm_bf16<<<ggemm, 64, 0, stream>>>(xqb, wtr, gtmp);
  ln_rows<<<T, 256, 0, stream>>>(gtmp, qbf, ln_r_g, ln_r_b, 0.125f);
  gemm_bf16<<<ggemm, 64, 0, stream>>>(xkb, wtk, gtmp);
  ln_rows<<<T, 256, 0, stream>>>(gtmp, kbf, ln_k_g, ln_k_b, 1.0f);
  gemm_bf16<<<ggemm, 64, 0, stream>>>(xvb, wtv, gtmp);
  ln_rows<<<T, 256, 0, stream>>>(gtmp, vbf, ln_v_g, ln_v_b, 1.0f);
  vtrans_kernel<<<dim3(T/32, C_DIM/32), 256, 0, stream>>>(vbf, Vt, T);

  attn_stats<<<dim3(8, T/TQ), 512, 0, stream>>>(
      qbf, kbf, hmb, part_m, part_l, T);
  ml_combine<<<(HEADS*T)/256, 256, 0, stream>>>(part_m, part_l, m_fin, linv, T);
  attn_apply<<<dim3(8, T/TQ), 512, 0, stream>>>(
      qbf, kbf, Vt, hmb, m_fin, linv, P, T);

  reduce_ln<<<T, 256, 0, stream>>>(P, abf, ln_x_g, ln_x_b, T);
  gemm_bf16<<<ggemm, 64, 0, stream>>>(abf, wto, (float*)d_out);
}